// Round 14
// baseline (367.697 us; speedup 1.0000x reference)
//
#include <hip/hip_runtime.h>
#include <hip/hip_bf16.h>

#define DIM 64
#define BM 128

typedef __attribute__((ext_vector_type(8))) short bf16x8;
typedef __attribute__((ext_vector_type(4))) float f32x4;

__device__ __forceinline__ short f2bf_hw(float x) {
    __hip_bfloat16 b = __float2bfloat16(x);
    return (short)reinterpret_cast<unsigned short&>(b);
}
__device__ __forceinline__ float bf2f_hw(unsigned short s) {
    return __uint_as_float(((unsigned)s) << 16);
}
// full split: hi+lo (3-term MFMA — R12 showed 2-term is SLOWER; MFMAs are free)
__device__ __forceinline__ void split8(f32x4 a, f32x4 b, bf16x8& hi, bf16x8& lo) {
    float v[8] = {a[0], a[1], a[2], a[3], b[0], b[1], b[2], b[3]};
    #pragma unroll
    for (int i = 0; i < 8; ++i) {
        short h = f2bf_hw(v[i]);
        hi[i] = h;
        lo[i] = f2bf_hw(v[i] - bf2f_hw((unsigned short)h));
    }
}
// XOR-swizzle (T2): byte address within act tile; row stride 256B
__device__ __forceinline__ int swz(int row, int colbyte) {
    return row * 256 + (colbyte ^ ((row & 7) << 4));
}

// ---- weight prep (first 128 blocks) + dst histogram (all blocks, grid-stride)
__global__ __launch_bounds__(256) void k_prep_hist(
    const float* __restrict__ We1, const float* __restrict__ We2,
    const float* __restrict__ Wp1, const float* __restrict__ Wp2,
    const float* __restrict__ Wh1, const float* __restrict__ Wh2,
    unsigned short* __restrict__ whi, unsigned short* __restrict__ wlo,
    const int* __restrict__ dst, int* __restrict__ cnt, int E)
{
    int t = blockIdx.x * 256 + threadIdx.x;
    if (t < 32768) {
        int e_ = t & 7, lane = (t >> 3) & 63, frag = (t >> 9) & 7, layer = t >> 12;
        int kt = frag >> 2, nt = frag & 3;
        int k = kt * 32 + ((lane >> 4) * 8) + e_;
        int n = nt * 16 + (lane & 15);
        const float* W;
        switch (layer) {
            case 0: W = We1; break;
            case 1: W = We2; break;
            case 2: W = Wp1; break;
            case 3: W = Wp2; break;
            case 4: W = Wh1; break;
            case 5: W = Wh2; break;
            case 6: W = Wp1 + 64 * 64; break;
            default: W = Wp1 + 128 * 64; break;
        }
        float w = W[k * 64 + n];
        short h = f2bf_hw(w);
        whi[t] = (unsigned short)h;
        wlo[t] = (unsigned short)f2bf_hw(w - bf2f_hw((unsigned short)h));
    }
    for (int i = t; i < E; i += gridDim.x * 256)
        atomicAdd(&cnt[dst[i]], 1);
}

// ---- node pipeline via MFMA: 128 nodes/block, 4 waves x 32 wave-private rows.
// z_h stored as bf16 (feeds only the alpha-weighted aggregate; halves gather BW)
__global__ __launch_bounds__(256) void node_mfma(
    const float* __restrict__ h,
    const unsigned short* __restrict__ whi, const unsigned short* __restrict__ wlo,
    const float* __restrict__ Wa,
    unsigned short* __restrict__ z_hb, float* __restrict__ u_s, float* __restrict__ u_d,
    float* __restrict__ as_, float* __restrict__ ad_, int N)
{
    __shared__ float act[BM * 64];
    char* lds = (char*)act;
    const int lane  = threadIdx.x & 63;
    const int wave  = threadIdx.x >> 6;
    const int wrow0 = wave * 32;
    const long node0 = (long)blockIdx.x * BM;
    const int g   = lane >> 4;
    const int c15 = lane & 15;

    f32x4 acc[2][4];
    auto zacc = [&]() {
        #pragma unroll
        for (int mt = 0; mt < 2; ++mt)
            #pragma unroll
            for (int nt = 0; nt < 4; ++nt)
                #pragma unroll
                for (int rr = 0; rr < 4; ++rr) acc[mt][nt][rr] = 0.f;
    };

    auto mfma_layer = [&](int layer) {
        #pragma unroll
        for (int kt = 0; kt < 2; ++kt) {
            bf16x8 ah[2], al[2];
            #pragma unroll
            for (int mt = 0; mt < 2; ++mt) {
                f32x4 a0, a1;
                if (layer == 4) {           // A from global h
                    long nr = node0 + wrow0 + mt * 16 + c15; if (nr >= N) nr = N - 1;
                    const f32x4* p = (const f32x4*)(h + nr * 64 + kt * 32 + g * 8);
                    a0 = p[0];
                    a1 = p[1];
                } else {
                    int row = wrow0 + mt * 16 + c15;
                    int cb  = kt * 128 + g * 32;
                    a0 = *(const f32x4*)(lds + swz(row, cb));
                    a1 = *(const f32x4*)(lds + swz(row, cb + 16));
                }
                split8(a0, a1, ah[mt], al[mt]);
            }
            __builtin_amdgcn_s_setprio(1);
            #pragma unroll
            for (int nt = 0; nt < 4; ++nt) {
                int fo = ((layer * 8 + kt * 4 + nt) * 64 + lane) * 8;
                bf16x8 bh = *(const bf16x8*)(whi + fo);
                bf16x8 bl = *(const bf16x8*)(wlo + fo);
                #pragma unroll
                for (int mt = 0; mt < 2; ++mt) {
                    acc[mt][nt] = __builtin_amdgcn_mfma_f32_16x16x32_bf16(ah[mt], bh, acc[mt][nt], 0, 0, 0);
                    acc[mt][nt] = __builtin_amdgcn_mfma_f32_16x16x32_bf16(ah[mt], bl, acc[mt][nt], 0, 0, 0);
                    acc[mt][nt] = __builtin_amdgcn_mfma_f32_16x16x32_bf16(al[mt], bh, acc[mt][nt], 0, 0, 0);
                }
            }
            __builtin_amdgcn_s_setprio(0);
        }
    };

    auto writeback = [&](bool relu) {
        #pragma unroll
        for (int mt = 0; mt < 2; ++mt)
            #pragma unroll
            for (int nt = 0; nt < 4; ++nt)
                #pragma unroll
                for (int rr = 0; rr < 4; ++rr) {
                    int row  = wrow0 + mt * 16 + g * 4 + rr;
                    int colb = (nt * 16 + c15) * 4;
                    float v = acc[mt][nt][rr];
                    if (relu) v = fmaxf(v, 0.f);
                    *(float*)(lds + swz(row, colb)) = v;
                }
    };

    auto store_global = [&](float* __restrict__ out) {
        #pragma unroll
        for (int mt = 0; mt < 2; ++mt)
            #pragma unroll
            for (int nt = 0; nt < 4; ++nt)
                #pragma unroll
                for (int rr = 0; rr < 4; ++rr) {
                    long nr = node0 + wrow0 + mt * 16 + g * 4 + rr; if (nr >= N) nr = N - 1;
                    out[nr * 64 + nt * 16 + c15] = acc[mt][nt][rr];
                }
    };

    // L1: t1 = relu(h @ Wh1)
    zacc(); mfma_layer(4); writeback(true);
    // L2: z_h = t1 @ Wh2
    zacc(); mfma_layer(5);

    // as = z_h . Wa[64:128], ad = z_h . Wa[128:192]  (Wa loaded at use)
    {
        float was[4], wad[4];
        #pragma unroll
        for (int nt = 0; nt < 4; ++nt) {
            was[nt] = Wa[64  + nt * 16 + c15];
            wad[nt] = Wa[128 + nt * 16 + c15];
        }
        #pragma unroll
        for (int mt = 0; mt < 2; ++mt) {
            float ps[4], pd[4];
            #pragma unroll
            for (int rr = 0; rr < 4; ++rr) {
                ps[rr] = acc[mt][0][rr] * was[0] + acc[mt][1][rr] * was[1]
                       + acc[mt][2][rr] * was[2] + acc[mt][3][rr] * was[3];
                pd[rr] = acc[mt][0][rr] * wad[0] + acc[mt][1][rr] * wad[1]
                       + acc[mt][2][rr] * wad[2] + acc[mt][3][rr] * wad[3];
            }
            #pragma unroll
            for (int off = 1; off < 16; off <<= 1)
                #pragma unroll
                for (int rr = 0; rr < 4; ++rr) {
                    ps[rr] += __shfl_xor(ps[rr], off);
                    pd[rr] += __shfl_xor(pd[rr], off);
                }
            if (c15 == 0) {
                #pragma unroll
                for (int rr = 0; rr < 4; ++rr) {
                    long nr = node0 + wrow0 + mt * 16 + g * 4 + rr; if (nr >= N) nr = N - 1;
                    as_[nr] = ps[rr];
                    ad_[nr] = pd[rr];
                }
            }
        }
    }
    // z_h -> global as bf16 (aggregate's only consumer)
    #pragma unroll
    for (int mt = 0; mt < 2; ++mt)
        #pragma unroll
        for (int nt = 0; nt < 4; ++nt)
            #pragma unroll
            for (int rr = 0; rr < 4; ++rr) {
                long nr = node0 + wrow0 + mt * 16 + g * 4 + rr; if (nr >= N) nr = N - 1;
                z_hb[nr * 64 + nt * 16 + c15] = (unsigned short)f2bf_hw(acc[mt][nt][rr]);
            }
    writeback(false);   // z_h -> LDS for L3/L4

    // L3: u_s = z_h @ Wp1[64:128]
    zacc(); mfma_layer(6); store_global(u_s);
    // L4: u_d = z_h @ Wp1[128:192]  (LDS still holds z_h)
    zacc(); mfma_layer(7); store_global(u_d);
}

// ---- edge pipeline (R13 structure, 3-term, e-loads-first). Attention scores
// scattered directly into CSR slots via pos[] (random STORE is fire-and-forget;
// removes aggregate's dependent random LOAD). uv gathers issued after L1
// (consumed at L3; latency covered by L2+attention; shorter reg lifetime).
__global__ __launch_bounds__(256) void edge_mfma(
    const float* __restrict__ e, const int* __restrict__ src, const int* __restrict__ dst,
    const float* __restrict__ u_s, const float* __restrict__ u_d,
    const float* __restrict__ as_, const float* __restrict__ ad_,
    const unsigned short* __restrict__ whi, const unsigned short* __restrict__ wlo,
    const float* __restrict__ Wa, const float* __restrict__ bp1, const float* __restrict__ bp2,
    const int* __restrict__ pos,
    float* __restrict__ eproj, float* __restrict__ abuf, int E)
{
    __shared__ float act[BM * 64];
    char* lds = (char*)act;
    const int lane  = threadIdx.x & 63;
    const int wave  = threadIdx.x >> 6;
    const int wrow0 = wave * 32;
    const long edge0 = (long)blockIdx.x * BM;
    const int g   = lane >> 4;
    const int c15 = lane & 15;

    // (1) e-row loads FIRST — retire before the gathers (vmcnt is in-order)
    f32x4 ea[2][2][2];   // [mt][kt][half]
    #pragma unroll
    for (int mt = 0; mt < 2; ++mt) {
        long er = edge0 + wrow0 + mt * 16 + c15; if (er >= E) er = E - 1;
        #pragma unroll
        for (int kt = 0; kt < 2; ++kt) {
            const f32x4* p = (const f32x4*)(e + er * 64 + kt * 32 + g * 8);
            ea[mt][kt][0] = __builtin_nontemporal_load(p);
            ea[mt][kt][1] = __builtin_nontemporal_load(p + 1);
        }
    }

    // (2) src/dst + asv gathers (consumed at attention, after L2)
    int sn[2][4], dn[2][4];
    float asv[2][4];
    #pragma unroll
    for (int mt = 0; mt < 2; ++mt)
        #pragma unroll
        for (int rr = 0; rr < 4; ++rr) {
            long er = edge0 + wrow0 + mt * 16 + g * 4 + rr; if (er >= E) er = E - 1;
            sn[mt][rr] = src[er]; dn[mt][rr] = dst[er];
            asv[mt][rr] = as_[sn[mt][rr]] + ad_[dn[mt][rr]];
        }

    f32x4 acc[2][4];
    auto zacc = [&]() {
        #pragma unroll
        for (int mt = 0; mt < 2; ++mt)
            #pragma unroll
            for (int nt = 0; nt < 4; ++nt)
                #pragma unroll
                for (int rr = 0; rr < 4; ++rr) acc[mt][nt][rr] = 0.f;
    };

    auto mfma_layer = [&](int layer) {
        #pragma unroll
        for (int kt = 0; kt < 2; ++kt) {
            bf16x8 ah[2], al[2];
            #pragma unroll
            for (int mt = 0; mt < 2; ++mt) {
                f32x4 a0, a1;
                if (layer == 0) {   // pre-loaded registers
                    a0 = ea[mt][kt][0];
                    a1 = ea[mt][kt][1];
                } else {
                    int row = wrow0 + mt * 16 + c15;
                    int cb  = kt * 128 + g * 32;
                    a0 = *(const f32x4*)(lds + swz(row, cb));
                    a1 = *(const f32x4*)(lds + swz(row, cb + 16));
                }
                split8(a0, a1, ah[mt], al[mt]);
            }
            __builtin_amdgcn_s_setprio(1);
            #pragma unroll
            for (int nt = 0; nt < 4; ++nt) {
                int fo = ((layer * 8 + kt * 4 + nt) * 64 + lane) * 8;
                bf16x8 bh = *(const bf16x8*)(whi + fo);
                bf16x8 bl = *(const bf16x8*)(wlo + fo);
                #pragma unroll
                for (int mt = 0; mt < 2; ++mt) {
                    acc[mt][nt] = __builtin_amdgcn_mfma_f32_16x16x32_bf16(ah[mt], bh, acc[mt][nt], 0, 0, 0);
                    acc[mt][nt] = __builtin_amdgcn_mfma_f32_16x16x32_bf16(ah[mt], bl, acc[mt][nt], 0, 0, 0);
                    acc[mt][nt] = __builtin_amdgcn_mfma_f32_16x16x32_bf16(al[mt], bh, acc[mt][nt], 0, 0, 0);
                }
            }
            __builtin_amdgcn_s_setprio(0);
        }
    };

    auto writeback = [&](bool relu) {
        #pragma unroll
        for (int mt = 0; mt < 2; ++mt)
            #pragma unroll
            for (int nt = 0; nt < 4; ++nt)
                #pragma unroll
                for (int rr = 0; rr < 4; ++rr) {
                    int row  = wrow0 + mt * 16 + g * 4 + rr;
                    int colb = (nt * 16 + c15) * 4;
                    float v = acc[mt][nt][rr];
                    if (relu) v = fmaxf(v, 0.f);
                    *(float*)(lds + swz(row, colb)) = v;
                }
    };

    // L1: t1 = relu(e @ We1)
    zacc(); mfma_layer(0); writeback(true);

    // (3) uv gathers issued here — consumed at L3 (covered by L2 + attention)
    float uv[2][4][4];
    #pragma unroll
    for (int mt = 0; mt < 2; ++mt)
        #pragma unroll
        for (int rr = 0; rr < 4; ++rr) {
            const float* us = u_s + (size_t)sn[mt][rr] * DIM;
            const float* ud = u_d + (size_t)dn[mt][rr] * DIM;
            #pragma unroll
            for (int nt = 0; nt < 4; ++nt)
                uv[mt][nt][rr] = us[nt * 16 + c15] + ud[nt * 16 + c15];
        }

    // L2: z_e = t1 @ We2
    zacc(); mfma_layer(1);

    // attention: ae = z_e . Wa[0:64]; a = relu(ae + asv); scatter into CSR slot
    {
        float waf[4];
        #pragma unroll
        for (int nt = 0; nt < 4; ++nt) waf[nt] = Wa[nt * 16 + c15];
        #pragma unroll
        for (int mt = 0; mt < 2; ++mt) {
            float part[4];
            #pragma unroll
            for (int rr = 0; rr < 4; ++rr)
                part[rr] = acc[mt][0][rr] * waf[0] + acc[mt][1][rr] * waf[1]
                         + acc[mt][2][rr] * waf[2] + acc[mt][3][rr] * waf[3];
            #pragma unroll
            for (int off = 1; off < 16; off <<= 1)
                #pragma unroll
                for (int rr = 0; rr < 4; ++rr) part[rr] += __shfl_xor(part[rr], off);
            if (c15 == 0) {
                #pragma unroll
                for (int rr = 0; rr < 4; ++rr) {
                    long er0 = edge0 + wrow0 + mt * 16 + g * 4 + rr;
                    if (er0 < E) {
                        int p = pos[er0];   // fire-and-forget chain: load -> store
                        abuf[p] = fmaxf(part[rr] + asv[mt][rr], 0.f);
                    }
                }
            }
        }
    }
    writeback(false);

    // L3: t2 = relu(z_e @ Wp1top + uv + bp1)
    zacc(); mfma_layer(2);
    {
        float b1f[4];
        #pragma unroll
        for (int nt = 0; nt < 4; ++nt) b1f[nt] = bp1[nt * 16 + c15];
        #pragma unroll
        for (int mt = 0; mt < 2; ++mt)
            #pragma unroll
            for (int nt = 0; nt < 4; ++nt)
                #pragma unroll
                for (int rr = 0; rr < 4; ++rr)
                    acc[mt][nt][rr] += uv[mt][nt][rr] + b1f[nt];
    }
    writeback(true);

    // L4: eproj = relu(t2 @ Wp2 + bp2)  — streaming write-once: nontemporal
    zacc(); mfma_layer(3);
    {
        float b2f[4];
        #pragma unroll
        for (int nt = 0; nt < 4; ++nt) b2f[nt] = bp2[nt * 16 + c15];
        #pragma unroll
        for (int mt = 0; mt < 2; ++mt)
            #pragma unroll
            for (int nt = 0; nt < 4; ++nt)
                #pragma unroll
                for (int rr = 0; rr < 4; ++rr) {
                    long er = edge0 + wrow0 + mt * 16 + g * 4 + rr; if (er >= E) er = E - 1;
                    __builtin_nontemporal_store(fmaxf(acc[mt][nt][rr] + b2f[nt], 0.f),
                                                eproj + er * 64 + nt * 16 + c15);
                }
    }
}

// ---- CSR scan ----
__global__ __launch_bounds__(256) void k_scan1(
    const int* __restrict__ cnt, int* __restrict__ ofs, int* __restrict__ bsum, int N)
{
    __shared__ int sm[256];
    int t = threadIdx.x, i = blockIdx.x * 256 + t;
    int v = (i < N) ? cnt[i] : 0;
    sm[t] = v;
    __syncthreads();
    #pragma unroll
    for (int off = 1; off < 256; off <<= 1) {
        int tmp = (t >= off) ? sm[t - off] : 0;
        __syncthreads();
        sm[t] += tmp;
        __syncthreads();
    }
    if (i < N) ofs[i] = sm[t] - v;
    if (t == 255) bsum[blockIdx.x] = sm[255];
}

__global__ __launch_bounds__(256) void k_scan2(int* __restrict__ bsum, int NB)
{
    __shared__ int sm[256];
    int t = threadIdx.x;
    int v = (t < NB) ? bsum[t] : 0;
    sm[t] = v;
    __syncthreads();
    #pragma unroll
    for (int off = 1; off < 256; off <<= 1) {
        int tmp = (t >= off) ? sm[t - off] : 0;
        __syncthreads();
        sm[t] += tmp;
        __syncthreads();
    }
    if (t < NB) bsum[t] = sm[t] - v;   // exclusive
}

__global__ __launch_bounds__(256) void k_scan3(
    int* __restrict__ ofs, int* __restrict__ cursor,
    const int* __restrict__ bsum, int N)
{
    int i = blockIdx.x * 256 + threadIdx.x;
    if (i < N) {
        int o = ofs[i] + bsum[blockIdx.x];
        ofs[i] = o;
        cursor[i] = o;
    }
}

// fill: esrc[slot]=src (for the aggregate gather), pos[edge]=slot (so edge_mfma
// can scatter its score straight into CSR order)
__global__ __launch_bounds__(256) void k_fill(
    const int* __restrict__ dst, const int* __restrict__ src,
    int* __restrict__ cursor, int* __restrict__ esrc, int* __restrict__ pos, int E)
{
    int i = blockIdx.x * 256 + threadIdx.x;
    if (i < E) {
        int p = atomicAdd(&cursor[dst[i]], 1);
        esrc[p] = src[i];
        pos[i] = p;
    }
}

// ---- fused segment softmax + weighted gather: 1 wave/node.
// Scores (abuf) are already CSR-ordered -> coalesced loads; only remaining
// random access is the z_hb (bf16) gather.
__global__ __launch_bounds__(256) void k_aggregate(
    const float* __restrict__ abuf, const int* __restrict__ esrc,
    const int* __restrict__ ofs, const int* __restrict__ cnt,
    const unsigned short* __restrict__ z_hb, float* __restrict__ hout, int N)
{
    int wid  = (blockIdx.x * 256 + threadIdx.x) >> 6;
    int lane = threadIdx.x & 63;
    if (wid >= N) return;
    int grp = lane >> 4, c15 = lane & 15;

    int begin = ofs[wid];
    int deg   = cnt[wid];

    float4 acc = make_float4(0.f, 0.f, 0.f, 0.f);
    float inv_s;

    if (deg <= 64) {
        float a = 0.f; int sidx = 0;
        if (lane < deg) {
            a    = abuf[begin + lane];   // coalesced
            sidx = esrc[begin + lane];   // coalesced
        }
        float m = a;
        #pragma unroll
        for (int off = 32; off; off >>= 1) m = fmaxf(m, __shfl_xor(m, off));

        float ex = (lane < deg) ? __expf(a - m) : 0.f;
        float s = ex;
        #pragma unroll
        for (int off = 32; off; off >>= 1) s += __shfl_xor(s, off);
        inv_s = 1.0f / fmaxf(s, 1e-9f);

        int trips = (deg + 3) >> 2;
        for (int i = 0; i < trips; ++i) {
            int k = grp + 4 * i;
            float w  = __shfl(ex,   k & 63);
            int   sk = __shfl(sidx, k & 63);
            if (k < deg) {
                const ushort4 v = *(const ushort4*)(z_hb + (size_t)sk * DIM + c15 * 4);
                acc.x = fmaf(w, bf2f_hw(v.x), acc.x);
                acc.y = fmaf(w, bf2f_hw(v.y), acc.y);
                acc.z = fmaf(w, bf2f_hw(v.z), acc.z);
                acc.w = fmaf(w, bf2f_hw(v.w), acc.w);
            }
        }
    } else {
        float m = 0.f;
        for (int k = lane; k < deg; k += 64) m = fmaxf(m, abuf[begin + k]);
        #pragma unroll
        for (int off = 32; off; off >>= 1) m = fmaxf(m, __shfl_xor(m, off));

        float s = 0.f;
        for (int k = lane; k < deg; k += 64) s += __expf(abuf[begin + k] - m);
        #pragma unroll
        for (int off = 32; off; off >>= 1) s += __shfl_xor(s, off);
        inv_s = 1.0f / fmaxf(s, 1e-9f);

        for (int k = grp; k < deg; k += 4) {
            float w = __expf(abuf[begin + k] - m);
            int  sk = esrc[begin + k];
            const ushort4 v = *(const ushort4*)(z_hb + (size_t)sk * DIM + c15 * 4);
            acc.x = fmaf(w, bf2f_hw(v.x), acc.x);
            acc.y = fmaf(w, bf2f_hw(v.y), acc.y);
            acc.z = fmaf(w, bf2f_hw(v.z), acc.z);
            acc.w = fmaf(w, bf2f_hw(v.w), acc.w);
        }
    }

    #pragma unroll
    for (int off = 16; off <= 32; off <<= 1) {
        acc.x += __shfl_xor(acc.x, off);
        acc.y += __shfl_xor(acc.y, off);
        acc.z += __shfl_xor(acc.z, off);
        acc.w += __shfl_xor(acc.w, off);
    }
    if (grp == 0) {
        float4 r = make_float4(fmaxf(acc.x * inv_s, 0.f), fmaxf(acc.y * inv_s, 0.f),
                               fmaxf(acc.z * inv_s, 0.f), fmaxf(acc.w * inv_s, 0.f));
        *(float4*)(hout + (size_t)wid * DIM + c15 * 4) = r;
    }
}

extern "C" void kernel_launch(void* const* d_in, const int* in_sizes, int n_in,
                              void* d_out, int out_size, void* d_ws, size_t ws_size,
                              hipStream_t stream)
{
    const float* h   = (const float*)d_in[0];
    const float* e   = (const float*)d_in[1];
    const int*   src = (const int*)d_in[2];
    const int*   dst = (const int*)d_in[3];
    const float* Wh1 = (const float*)d_in[4];
    const float* Wh2 = (const float*)d_in[5];
    const float* We1 = (const float*)d_in[6];
    const float* We2 = (const float*)d_in[7];
    const float* Wp1 = (const float*)d_in[8];
    const float* bp1 = (const float*)d_in[9];
    const float* Wp2 = (const float*)d_in[10];
    const float* bp2 = (const float*)d_in[11];
    const float* Wa  = (const float*)d_in[12];

    const int N = in_sizes[0] / DIM;
    const int E = in_sizes[1] / DIM;

    float* ws   = (float*)d_ws;
    unsigned short* z_hb = (unsigned short*)ws;  ws += (size_t)N * DIM / 2;
    float* u_s  = ws;  ws += (size_t)N * DIM;
    float* u_d  = ws;  ws += (size_t)N * DIM;
    float* as_  = ws;  ws += N;
    float* ad_  = ws;  ws += N;
    float* abuf = ws;  ws += E;
    int* cnt    = (int*)ws;  ws += N;
    int* ofs    = (int*)ws;  ws += N;
    int* cursor = (int*)ws;  ws += N;
    int* esrc   = (int*)ws;  ws += E;
    int* pos    = (int*)ws;  ws += E;
    int* bsum   = (int*)ws;  ws += 256;
    unsigned short* whi = (unsigned short*)ws;  ws += 32768 / 2;
    unsigned short* wlo = (unsigned short*)ws;  ws += 32768 / 2;

    float* hout  = (float*)d_out;
    float* eproj = hout + (size_t)N * DIM;

    const int NB = (N + 255) / 256;   // N=50000 -> 196 <= 256

    hipMemsetAsync(cnt, 0, (size_t)N * sizeof(int), stream);

    k_prep_hist<<<(E + 255) / 256, 256, 0, stream>>>(
        We1, We2, Wp1, Wp2, Wh1, Wh2, whi, wlo, dst, cnt, E);

    k_scan1<<<NB, 256, 0, stream>>>(cnt, ofs, bsum, N);
    k_scan2<<<1, 256, 0, stream>>>(bsum, NB);
    k_scan3<<<NB, 256, 0, stream>>>(ofs, cursor, bsum, N);
    k_fill<<<(E + 255) / 256, 256, 0, stream>>>(dst, src, cursor, esrc, pos, E);

    node_mfma<<<(N + BM - 1) / BM, 256, 0, stream>>>(
        h, whi, wlo, Wa, z_hb, u_s, u_d, as_, ad_, N);

    edge_mfma<<<(E + BM - 1) / BM, 256, 0, stream>>>(
        e, src, dst, u_s, u_d, as_, ad_, whi, wlo, Wa, bp1, bp2, pos,
        eproj, abuf, E);

    k_aggregate<<<((N * 64) + 255) / 256, 256, 0, stream>>>(
        abuf, esrc, ofs, cnt, z_hb, hout, N);
}

// Round 15
// 331.025 us; speedup vs baseline: 1.1108x; 1.1108x over previous
//
#include <hip/hip_runtime.h>
#include <hip/hip_bf16.h>

#define DIM 64
#define BM 128

typedef __attribute__((ext_vector_type(8))) short bf16x8;
typedef __attribute__((ext_vector_type(4))) float f32x4;

__device__ __forceinline__ short f2bf_hw(float x) {
    __hip_bfloat16 b = __float2bfloat16(x);
    return (short)reinterpret_cast<unsigned short&>(b);
}
__device__ __forceinline__ float bf2f_hw(unsigned short s) {
    return __uint_as_float(((unsigned)s) << 16);
}
// full split: hi+lo (3-term MFMA — R12 showed 2-term is SLOWER; MFMAs are free)
__device__ __forceinline__ void split8(f32x4 a, f32x4 b, bf16x8& hi, bf16x8& lo) {
    float v[8] = {a[0], a[1], a[2], a[3], b[0], b[1], b[2], b[3]};
    #pragma unroll
    for (int i = 0; i < 8; ++i) {
        short h = f2bf_hw(v[i]);
        hi[i] = h;
        lo[i] = f2bf_hw(v[i] - bf2f_hw((unsigned short)h));
    }
}
// XOR-swizzle (T2): byte address within act tile; row stride 256B
__device__ __forceinline__ int swz(int row, int colbyte) {
    return row * 256 + (colbyte ^ ((row & 7) << 4));
}

// ---- weight prep (first 128 blocks) + dst histogram (all blocks, grid-stride)
__global__ __launch_bounds__(256) void k_prep_hist(
    const float* __restrict__ We1, const float* __restrict__ We2,
    const float* __restrict__ Wp1, const float* __restrict__ Wp2,
    const float* __restrict__ Wh1, const float* __restrict__ Wh2,
    unsigned short* __restrict__ whi, unsigned short* __restrict__ wlo,
    const int* __restrict__ dst, int* __restrict__ cnt, int E)
{
    int t = blockIdx.x * 256 + threadIdx.x;
    if (t < 32768) {
        int e_ = t & 7, lane = (t >> 3) & 63, frag = (t >> 9) & 7, layer = t >> 12;
        int kt = frag >> 2, nt = frag & 3;
        int k = kt * 32 + ((lane >> 4) * 8) + e_;
        int n = nt * 16 + (lane & 15);
        const float* W;
        switch (layer) {
            case 0: W = We1; break;
            case 1: W = We2; break;
            case 2: W = Wp1; break;
            case 3: W = Wp2; break;
            case 4: W = Wh1; break;
            case 5: W = Wh2; break;
            case 6: W = Wp1 + 64 * 64; break;
            default: W = Wp1 + 128 * 64; break;
        }
        float w = W[k * 64 + n];
        short h = f2bf_hw(w);
        whi[t] = (unsigned short)h;
        wlo[t] = (unsigned short)f2bf_hw(w - bf2f_hw((unsigned short)h));
    }
    for (int i = t; i < E; i += gridDim.x * 256)
        atomicAdd(&cnt[dst[i]], 1);
}

// ---- node pipeline via MFMA: 128 nodes/block, 4 waves x 32 wave-private rows.
// z_h stored as bf16 (feeds only the alpha-weighted aggregate; halves gather BW;
// R14 proved absmax unchanged at 0.0078)
__global__ __launch_bounds__(256) void node_mfma(
    const float* __restrict__ h,
    const unsigned short* __restrict__ whi, const unsigned short* __restrict__ wlo,
    const float* __restrict__ Wa,
    unsigned short* __restrict__ z_hb, float* __restrict__ u_s, float* __restrict__ u_d,
    float* __restrict__ as_, float* __restrict__ ad_, int N)
{
    __shared__ float act[BM * 64];
    char* lds = (char*)act;
    const int lane  = threadIdx.x & 63;
    const int wave  = threadIdx.x >> 6;
    const int wrow0 = wave * 32;
    const long node0 = (long)blockIdx.x * BM;
    const int g   = lane >> 4;
    const int c15 = lane & 15;

    f32x4 acc[2][4];
    auto zacc = [&]() {
        #pragma unroll
        for (int mt = 0; mt < 2; ++mt)
            #pragma unroll
            for (int nt = 0; nt < 4; ++nt)
                #pragma unroll
                for (int rr = 0; rr < 4; ++rr) acc[mt][nt][rr] = 0.f;
    };

    auto mfma_layer = [&](int layer) {
        #pragma unroll
        for (int kt = 0; kt < 2; ++kt) {
            bf16x8 ah[2], al[2];
            #pragma unroll
            for (int mt = 0; mt < 2; ++mt) {
                f32x4 a0, a1;
                if (layer == 4) {           // A from global h
                    long nr = node0 + wrow0 + mt * 16 + c15; if (nr >= N) nr = N - 1;
                    const f32x4* p = (const f32x4*)(h + nr * 64 + kt * 32 + g * 8);
                    a0 = p[0];
                    a1 = p[1];
                } else {
                    int row = wrow0 + mt * 16 + c15;
                    int cb  = kt * 128 + g * 32;
                    a0 = *(const f32x4*)(lds + swz(row, cb));
                    a1 = *(const f32x4*)(lds + swz(row, cb + 16));
                }
                split8(a0, a1, ah[mt], al[mt]);
            }
            __builtin_amdgcn_s_setprio(1);
            #pragma unroll
            for (int nt = 0; nt < 4; ++nt) {
                int fo = ((layer * 8 + kt * 4 + nt) * 64 + lane) * 8;
                bf16x8 bh = *(const bf16x8*)(whi + fo);
                bf16x8 bl = *(const bf16x8*)(wlo + fo);
                #pragma unroll
                for (int mt = 0; mt < 2; ++mt) {
                    acc[mt][nt] = __builtin_amdgcn_mfma_f32_16x16x32_bf16(ah[mt], bh, acc[mt][nt], 0, 0, 0);
                    acc[mt][nt] = __builtin_amdgcn_mfma_f32_16x16x32_bf16(ah[mt], bl, acc[mt][nt], 0, 0, 0);
                    acc[mt][nt] = __builtin_amdgcn_mfma_f32_16x16x32_bf16(al[mt], bh, acc[mt][nt], 0, 0, 0);
                }
            }
            __builtin_amdgcn_s_setprio(0);
        }
    };

    auto writeback = [&](bool relu) {
        #pragma unroll
        for (int mt = 0; mt < 2; ++mt)
            #pragma unroll
            for (int nt = 0; nt < 4; ++nt)
                #pragma unroll
                for (int rr = 0; rr < 4; ++rr) {
                    int row  = wrow0 + mt * 16 + g * 4 + rr;
                    int colb = (nt * 16 + c15) * 4;
                    float v = acc[mt][nt][rr];
                    if (relu) v = fmaxf(v, 0.f);
                    *(float*)(lds + swz(row, colb)) = v;
                }
    };

    auto store_global = [&](float* __restrict__ out) {
        #pragma unroll
        for (int mt = 0; mt < 2; ++mt)
            #pragma unroll
            for (int nt = 0; nt < 4; ++nt)
                #pragma unroll
                for (int rr = 0; rr < 4; ++rr) {
                    long nr = node0 + wrow0 + mt * 16 + g * 4 + rr; if (nr >= N) nr = N - 1;
                    out[nr * 64 + nt * 16 + c15] = acc[mt][nt][rr];
                }
    };

    // L1: t1 = relu(h @ Wh1)
    zacc(); mfma_layer(4); writeback(true);
    // L2: z_h = t1 @ Wh2
    zacc(); mfma_layer(5);

    // as = z_h . Wa[64:128], ad = z_h . Wa[128:192]  (Wa loaded at use)
    {
        float was[4], wad[4];
        #pragma unroll
        for (int nt = 0; nt < 4; ++nt) {
            was[nt] = Wa[64  + nt * 16 + c15];
            wad[nt] = Wa[128 + nt * 16 + c15];
        }
        #pragma unroll
        for (int mt = 0; mt < 2; ++mt) {
            float ps[4], pd[4];
            #pragma unroll
            for (int rr = 0; rr < 4; ++rr) {
                ps[rr] = acc[mt][0][rr] * was[0] + acc[mt][1][rr] * was[1]
                       + acc[mt][2][rr] * was[2] + acc[mt][3][rr] * was[3];
                pd[rr] = acc[mt][0][rr] * wad[0] + acc[mt][1][rr] * wad[1]
                       + acc[mt][2][rr] * wad[2] + acc[mt][3][rr] * wad[3];
            }
            #pragma unroll
            for (int off = 1; off < 16; off <<= 1)
                #pragma unroll
                for (int rr = 0; rr < 4; ++rr) {
                    ps[rr] += __shfl_xor(ps[rr], off);
                    pd[rr] += __shfl_xor(pd[rr], off);
                }
            if (c15 == 0) {
                #pragma unroll
                for (int rr = 0; rr < 4; ++rr) {
                    long nr = node0 + wrow0 + mt * 16 + g * 4 + rr; if (nr >= N) nr = N - 1;
                    as_[nr] = ps[rr];
                    ad_[nr] = pd[rr];
                }
            }
        }
    }
    // z_h -> global as bf16 (aggregate's only consumer)
    #pragma unroll
    for (int mt = 0; mt < 2; ++mt)
        #pragma unroll
        for (int nt = 0; nt < 4; ++nt)
            #pragma unroll
            for (int rr = 0; rr < 4; ++rr) {
                long nr = node0 + wrow0 + mt * 16 + g * 4 + rr; if (nr >= N) nr = N - 1;
                z_hb[nr * 64 + nt * 16 + c15] = (unsigned short)f2bf_hw(acc[mt][nt][rr]);
            }
    writeback(false);   // z_h -> LDS for L3/L4

    // L3: u_s = z_h @ Wp1[64:128]
    zacc(); mfma_layer(6); store_global(u_s);
    // L4: u_d = z_h @ Wp1[128:192]  (LDS still holds z_h)
    zacc(); mfma_layer(7); store_global(u_d);
}

// ---- edge pipeline (R13 EXACTLY — the 200µs local optimum: e-loads first,
// then src/dst+uv/asv prefetch, 3-term, nontemporal streaming, abuf by edge id)
__global__ __launch_bounds__(256) void edge_mfma(
    const float* __restrict__ e, const int* __restrict__ src, const int* __restrict__ dst,
    const float* __restrict__ u_s, const float* __restrict__ u_d,
    const float* __restrict__ as_, const float* __restrict__ ad_,
    const unsigned short* __restrict__ whi, const unsigned short* __restrict__ wlo,
    const float* __restrict__ Wa, const float* __restrict__ bp1, const float* __restrict__ bp2,
    float* __restrict__ eproj, float* __restrict__ abuf, int E)
{
    __shared__ float act[BM * 64];
    char* lds = (char*)act;
    const int lane  = threadIdx.x & 63;
    const int wave  = threadIdx.x >> 6;
    const int wrow0 = wave * 32;
    const long edge0 = (long)blockIdx.x * BM;
    const int g   = lane >> 4;
    const int c15 = lane & 15;

    // (1) e-row loads FIRST — retire before the gathers (vmcnt is in-order)
    f32x4 ea[2][2][2];   // [mt][kt][half]
    #pragma unroll
    for (int mt = 0; mt < 2; ++mt) {
        long er = edge0 + wrow0 + mt * 16 + c15; if (er >= E) er = E - 1;
        #pragma unroll
        for (int kt = 0; kt < 2; ++kt) {
            const f32x4* p = (const f32x4*)(e + er * 64 + kt * 32 + g * 8);
            ea[mt][kt][0] = __builtin_nontemporal_load(p);
            ea[mt][kt][1] = __builtin_nontemporal_load(p + 1);
        }
    }

    // (2) per-edge gathers issued second — consumed at attention / L3
    float uv[2][4][4], asv[2][4];
    #pragma unroll
    for (int mt = 0; mt < 2; ++mt)
        #pragma unroll
        for (int rr = 0; rr < 4; ++rr) {
            long er = edge0 + wrow0 + mt * 16 + g * 4 + rr; if (er >= E) er = E - 1;
            int sn = src[er], dn = dst[er];
            const float* us = u_s + (size_t)sn * DIM;
            const float* ud = u_d + (size_t)dn * DIM;
            #pragma unroll
            for (int nt = 0; nt < 4; ++nt)
                uv[mt][nt][rr] = us[nt * 16 + c15] + ud[nt * 16 + c15];
            asv[mt][rr] = as_[sn] + ad_[dn];
        }

    f32x4 acc[2][4];
    auto zacc = [&]() {
        #pragma unroll
        for (int mt = 0; mt < 2; ++mt)
            #pragma unroll
            for (int nt = 0; nt < 4; ++nt)
                #pragma unroll
                for (int rr = 0; rr < 4; ++rr) acc[mt][nt][rr] = 0.f;
    };

    auto mfma_layer = [&](int layer) {
        #pragma unroll
        for (int kt = 0; kt < 2; ++kt) {
            bf16x8 ah[2], al[2];
            #pragma unroll
            for (int mt = 0; mt < 2; ++mt) {
                f32x4 a0, a1;
                if (layer == 0) {   // pre-loaded registers
                    a0 = ea[mt][kt][0];
                    a1 = ea[mt][kt][1];
                } else {
                    int row = wrow0 + mt * 16 + c15;
                    int cb  = kt * 128 + g * 32;
                    a0 = *(const f32x4*)(lds + swz(row, cb));
                    a1 = *(const f32x4*)(lds + swz(row, cb + 16));
                }
                split8(a0, a1, ah[mt], al[mt]);
            }
            __builtin_amdgcn_s_setprio(1);
            #pragma unroll
            for (int nt = 0; nt < 4; ++nt) {
                int fo = ((layer * 8 + kt * 4 + nt) * 64 + lane) * 8;
                bf16x8 bh = *(const bf16x8*)(whi + fo);
                bf16x8 bl = *(const bf16x8*)(wlo + fo);
                #pragma unroll
                for (int mt = 0; mt < 2; ++mt) {
                    acc[mt][nt] = __builtin_amdgcn_mfma_f32_16x16x32_bf16(ah[mt], bh, acc[mt][nt], 0, 0, 0);
                    acc[mt][nt] = __builtin_amdgcn_mfma_f32_16x16x32_bf16(ah[mt], bl, acc[mt][nt], 0, 0, 0);
                    acc[mt][nt] = __builtin_amdgcn_mfma_f32_16x16x32_bf16(al[mt], bh, acc[mt][nt], 0, 0, 0);
                }
            }
            __builtin_amdgcn_s_setprio(0);
        }
    };

    auto writeback = [&](bool relu) {
        #pragma unroll
        for (int mt = 0; mt < 2; ++mt)
            #pragma unroll
            for (int nt = 0; nt < 4; ++nt)
                #pragma unroll
                for (int rr = 0; rr < 4; ++rr) {
                    int row  = wrow0 + mt * 16 + g * 4 + rr;
                    int colb = (nt * 16 + c15) * 4;
                    float v = acc[mt][nt][rr];
                    if (relu) v = fmaxf(v, 0.f);
                    *(float*)(lds + swz(row, colb)) = v;
                }
    };

    // L1: t1 = relu(e @ We1)
    zacc(); mfma_layer(0); writeback(true);
    // L2: z_e = t1 @ We2
    zacc(); mfma_layer(1);

    // attention: ae = z_e . Wa[0:64]; a = relu(ae + as[src] + ad[dst])
    {
        float waf[4];
        #pragma unroll
        for (int nt = 0; nt < 4; ++nt) waf[nt] = Wa[nt * 16 + c15];
        #pragma unroll
        for (int mt = 0; mt < 2; ++mt) {
            float part[4];
            #pragma unroll
            for (int rr = 0; rr < 4; ++rr)
                part[rr] = acc[mt][0][rr] * waf[0] + acc[mt][1][rr] * waf[1]
                         + acc[mt][2][rr] * waf[2] + acc[mt][3][rr] * waf[3];
            #pragma unroll
            for (int off = 1; off < 16; off <<= 1)
                #pragma unroll
                for (int rr = 0; rr < 4; ++rr) part[rr] += __shfl_xor(part[rr], off);
            if (c15 == 0) {
                #pragma unroll
                for (int rr = 0; rr < 4; ++rr) {
                    long er = edge0 + wrow0 + mt * 16 + g * 4 + rr; if (er >= E) er = E - 1;
                    __builtin_nontemporal_store(fmaxf(part[rr] + asv[mt][rr], 0.f), abuf + er);
                }
            }
        }
    }
    writeback(false);

    // L3: t2 = relu(z_e @ Wp1top + uv + bp1)
    zacc(); mfma_layer(2);
    {
        float b1f[4];
        #pragma unroll
        for (int nt = 0; nt < 4; ++nt) b1f[nt] = bp1[nt * 16 + c15];
        #pragma unroll
        for (int mt = 0; mt < 2; ++mt)
            #pragma unroll
            for (int nt = 0; nt < 4; ++nt)
                #pragma unroll
                for (int rr = 0; rr < 4; ++rr)
                    acc[mt][nt][rr] += uv[mt][nt][rr] + b1f[nt];
    }
    writeback(true);

    // L4: eproj = relu(t2 @ Wp2 + bp2)  — streaming write-once: nontemporal
    zacc(); mfma_layer(3);
    {
        float b2f[4];
        #pragma unroll
        for (int nt = 0; nt < 4; ++nt) b2f[nt] = bp2[nt * 16 + c15];
        #pragma unroll
        for (int mt = 0; mt < 2; ++mt)
            #pragma unroll
            for (int nt = 0; nt < 4; ++nt)
                #pragma unroll
                for (int rr = 0; rr < 4; ++rr) {
                    long er = edge0 + wrow0 + mt * 16 + g * 4 + rr; if (er >= E) er = E - 1;
                    __builtin_nontemporal_store(fmaxf(acc[mt][nt][rr] + b2f[nt], 0.f),
                                                eproj + er * 64 + nt * 16 + c15);
                }
    }
}

// ---- CSR scan ----
__global__ __launch_bounds__(256) void k_scan1(
    const int* __restrict__ cnt, int* __restrict__ ofs, int* __restrict__ bsum, int N)
{
    __shared__ int sm[256];
    int t = threadIdx.x, i = blockIdx.x * 256 + t;
    int v = (i < N) ? cnt[i] : 0;
    sm[t] = v;
    __syncthreads();
    #pragma unroll
    for (int off = 1; off < 256; off <<= 1) {
        int tmp = (t >= off) ? sm[t - off] : 0;
        __syncthreads();
        sm[t] += tmp;
        __syncthreads();
    }
    if (i < N) ofs[i] = sm[t] - v;
    if (t == 255) bsum[blockIdx.x] = sm[255];
}

__global__ __launch_bounds__(256) void k_scan2(int* __restrict__ bsum, int NB)
{
    __shared__ int sm[256];
    int t = threadIdx.x;
    int v = (t < NB) ? bsum[t] : 0;
    sm[t] = v;
    __syncthreads();
    #pragma unroll
    for (int off = 1; off < 256; off <<= 1) {
        int tmp = (t >= off) ? sm[t - off] : 0;
        __syncthreads();
        sm[t] += tmp;
        __syncthreads();
    }
    if (t < NB) bsum[t] = sm[t] - v;   // exclusive
}

__global__ __launch_bounds__(256) void k_scan3(
    int* __restrict__ ofs, int* __restrict__ cursor,
    const int* __restrict__ bsum, int N)
{
    int i = blockIdx.x * 256 + threadIdx.x;
    if (i < N) {
        int o = ofs[i] + bsum[blockIdx.x];
        ofs[i] = o;
        cursor[i] = o;
    }
}

// fill packs (edge id, src node) so aggregate has one fewer dependent gather
__global__ __launch_bounds__(256) void k_fill(
    const int* __restrict__ dst, const int* __restrict__ src,
    int* __restrict__ cursor, int2* __restrict__ esrc, int E)
{
    int i = blockIdx.x * 256 + threadIdx.x;
    if (i < E) {
        int p = atomicAdd(&cursor[dst[i]], 1);
        esrc[p] = make_int2(i, src[i]);
    }
}

// ---- fused segment softmax + weighted gather: 1 wave/node.
// z_h gathered as bf16 (ushort4, 8B/lane) — half the random-read bytes.
__global__ __launch_bounds__(256) void k_aggregate(
    const float* __restrict__ abuf, const int2* __restrict__ esrc,
    const int* __restrict__ ofs, const int* __restrict__ cnt,
    const unsigned short* __restrict__ z_hb, float* __restrict__ hout, int N)
{
    int wid  = (blockIdx.x * 256 + threadIdx.x) >> 6;
    int lane = threadIdx.x & 63;
    if (wid >= N) return;
    int grp = lane >> 4, c15 = lane & 15;

    int begin = ofs[wid];
    int deg   = cnt[wid];

    float4 acc = make_float4(0.f, 0.f, 0.f, 0.f);
    float inv_s;

    if (deg <= 64) {
        float a = 0.f; int sidx = 0;
        if (lane < deg) {
            int2 es = esrc[begin + lane];
            a    = abuf[es.x];
            sidx = es.y;
        }
        float m = a;
        #pragma unroll
        for (int off = 32; off; off >>= 1) m = fmaxf(m, __shfl_xor(m, off));

        float ex = (lane < deg) ? __expf(a - m) : 0.f;
        float s = ex;
        #pragma unroll
        for (int off = 32; off; off >>= 1) s += __shfl_xor(s, off);
        inv_s = 1.0f / fmaxf(s, 1e-9f);

        int trips = (deg + 3) >> 2;
        for (int i = 0; i < trips; ++i) {
            int k = grp + 4 * i;
            float w  = __shfl(ex,   k & 63);
            int   sk = __shfl(sidx, k & 63);
            if (k < deg) {
                const ushort4 v = *(const ushort4*)(z_hb + (size_t)sk * DIM + c15 * 4);
                acc.x = fmaf(w, bf2f_hw(v.x), acc.x);
                acc.y = fmaf(w, bf2f_hw(v.y), acc.y);
                acc.z = fmaf(w, bf2f_hw(v.z), acc.z);
                acc.w = fmaf(w, bf2f_hw(v.w), acc.w);
            }
        }
    } else {
        float m = 0.f;
        for (int k = lane; k < deg; k += 64) m = fmaxf(m, abuf[esrc[begin + k].x]);
        #pragma unroll
        for (int off = 32; off; off >>= 1) m = fmaxf(m, __shfl_xor(m, off));

        float s = 0.f;
        for (int k = lane; k < deg; k += 64) s += __expf(abuf[esrc[begin + k].x] - m);
        #pragma unroll
        for (int off = 32; off; off >>= 1) s += __shfl_xor(s, off);
        inv_s = 1.0f / fmaxf(s, 1e-9f);

        for (int k = grp; k < deg; k += 4) {
            int2 es = esrc[begin + k];
            float w = __expf(abuf[es.x] - m);
            const ushort4 v = *(const ushort4*)(z_hb + (size_t)es.y * DIM + c15 * 4);
            acc.x = fmaf(w, bf2f_hw(v.x), acc.x);
            acc.y = fmaf(w, bf2f_hw(v.y), acc.y);
            acc.z = fmaf(w, bf2f_hw(v.z), acc.z);
            acc.w = fmaf(w, bf2f_hw(v.w), acc.w);
        }
    }

    #pragma unroll
    for (int off = 16; off <= 32; off <<= 1) {
        acc.x += __shfl_xor(acc.x, off);
        acc.y += __shfl_xor(acc.y, off);
        acc.z += __shfl_xor(acc.z, off);
        acc.w += __shfl_xor(acc.w, off);
    }
    if (grp == 0) {
        float4 r = make_float4(fmaxf(acc.x * inv_s, 0.f), fmaxf(acc.y * inv_s, 0.f),
                               fmaxf(acc.z * inv_s, 0.f), fmaxf(acc.w * inv_s, 0.f));
        *(float4*)(hout + (size_t)wid * DIM + c15 * 4) = r;
    }
}

extern "C" void kernel_launch(void* const* d_in, const int* in_sizes, int n_in,
                              void* d_out, int out_size, void* d_ws, size_t ws_size,
                              hipStream_t stream)
{
    const float* h   = (const float*)d_in[0];
    const float* e   = (const float*)d_in[1];
    const int*   src = (const int*)d_in[2];
    const int*   dst = (const int*)d_in[3];
    const float* Wh1 = (const float*)d_in[4];
    const float* Wh2 = (const float*)d_in[5];
    const float* We1 = (const float*)d_in[6];
    const float* We2 = (const float*)d_in[7];
    const float* Wp1 = (const float*)d_in[8];
    const float* bp1 = (const float*)d_in[9];
    const float* Wp2 = (const float*)d_in[10];
    const float* bp2 = (const float*)d_in[11];
    const float* Wa  = (const float*)d_in[12];

    const int N = in_sizes[0] / DIM;
    const int E = in_sizes[1] / DIM;

    float* ws   = (float*)d_ws;
    unsigned short* z_hb = (unsigned short*)ws;  ws += (size_t)N * DIM / 2;
    float* u_s  = ws;  ws += (size_t)N * DIM;
    float* u_d  = ws;  ws += (size_t)N * DIM;
    float* as_  = ws;  ws += N;
    float* ad_  = ws;  ws += N;
    float* abuf = ws;  ws += E;
    int* cnt    = (int*)ws;  ws += N;
    int* ofs    = (int*)ws;  ws += N;
    int* cursor = (int*)ws;  ws += N;
    int2* esrc  = (int2*)ws; ws += (size_t)2 * E;
    int* bsum   = (int*)ws;  ws += 256;
    unsigned short* whi = (unsigned short*)ws;  ws += 32768 / 2;
    unsigned short* wlo = (unsigned short*)ws;  ws += 32768 / 2;

    float* hout  = (float*)d_out;
    float* eproj = hout + (size_t)N * DIM;

    const int NB = (N + 255) / 256;   // N=50000 -> 196 <= 256

    hipMemsetAsync(cnt, 0, (size_t)N * sizeof(int), stream);

    k_prep_hist<<<(E + 255) / 256, 256, 0, stream>>>(
        We1, We2, Wp1, Wp2, Wh1, Wh2, whi, wlo, dst, cnt, E);

    k_scan1<<<NB, 256, 0, stream>>>(cnt, ofs, bsum, N);
    k_scan2<<<1, 256, 0, stream>>>(bsum, NB);
    k_scan3<<<NB, 256, 0, stream>>>(ofs, cursor, bsum, N);
    k_fill<<<(E + 255) / 256, 256, 0, stream>>>(dst, src, cursor, esrc, E);

    node_mfma<<<(N + BM - 1) / BM, 256, 0, stream>>>(
        h, whi, wlo, Wa, z_hb, u_s, u_d, as_, ad_, N);

    edge_mfma<<<(E + BM - 1) / BM, 256, 0, stream>>>(
        e, src, dst, u_s, u_d, as_, ad_, whi, wlo, Wa, bp1, bp2,
        eproj, abuf, E);

    k_aggregate<<<((N * 64) + 255) / 256, 256, 0, stream>>>(
        abuf, esrc, ofs, cnt, z_hb, hout, N);
}

// Round 16
// 313.165 us; speedup vs baseline: 1.1741x; 1.0570x over previous
//
#include <hip/hip_runtime.h>
#include <hip/hip_bf16.h>

#define DIM 64
#define BM 128

typedef __attribute__((ext_vector_type(8))) short bf16x8;
typedef __attribute__((ext_vector_type(4))) float f32x4;

__device__ __forceinline__ short f2bf_hw(float x) {
    __hip_bfloat16 b = __float2bfloat16(x);
    return (short)reinterpret_cast<unsigned short&>(b);
}
__device__ __forceinline__ float bf2f_hw(unsigned short s) {
    return __uint_as_float(((unsigned)s) << 16);
}
// full split: hi+lo (3-term MFMA — R12 showed 2-term is SLOWER; MFMAs are free)
__device__ __forceinline__ void split8(f32x4 a, f32x4 b, bf16x8& hi, bf16x8& lo) {
    float v[8] = {a[0], a[1], a[2], a[3], b[0], b[1], b[2], b[3]};
    #pragma unroll
    for (int i = 0; i < 8; ++i) {
        short h = f2bf_hw(v[i]);
        hi[i] = h;
        lo[i] = f2bf_hw(v[i] - bf2f_hw((unsigned short)h));
    }
}
// XOR-swizzle (T2): byte address within act tile; row stride 256B
__device__ __forceinline__ int swz(int row, int colbyte) {
    return row * 256 + (colbyte ^ ((row & 7) << 4));
}

// ---- weight prep (first 128 blocks) + dst histogram (all blocks, grid-stride)
__global__ __launch_bounds__(256) void k_prep_hist(
    const float* __restrict__ We1, const float* __restrict__ We2,
    const float* __restrict__ Wp1, const float* __restrict__ Wp2,
    const float* __restrict__ Wh1, const float* __restrict__ Wh2,
    unsigned short* __restrict__ whi, unsigned short* __restrict__ wlo,
    const int* __restrict__ dst, int* __restrict__ cnt, int E)
{
    int t = blockIdx.x * 256 + threadIdx.x;
    if (t < 32768) {
        int e_ = t & 7, lane = (t >> 3) & 63, frag = (t >> 9) & 7, layer = t >> 12;
        int kt = frag >> 2, nt = frag & 3;
        int k = kt * 32 + ((lane >> 4) * 8) + e_;
        int n = nt * 16 + (lane & 15);
        const float* W;
        switch (layer) {
            case 0: W = We1; break;
            case 1: W = We2; break;
            case 2: W = Wp1; break;
            case 3: W = Wp2; break;
            case 4: W = Wh1; break;
            case 5: W = Wh2; break;
            case 6: W = Wp1 + 64 * 64; break;
            default: W = Wp1 + 128 * 64; break;
        }
        float w = W[k * 64 + n];
        short h = f2bf_hw(w);
        whi[t] = (unsigned short)h;
        wlo[t] = (unsigned short)f2bf_hw(w - bf2f_hw((unsigned short)h));
    }
    for (int i = t; i < E; i += gridDim.x * 256)
        atomicAdd(&cnt[dst[i]], 1);
}

// ---- node pipeline via MFMA: 128 nodes/block, 4 waves x 32 wave-private rows.
// z_h AND u_s/u_d stored as bf16. u_s/u_d use fragment-major layout
// [node][c15][nt] so edge's per-lane gather is one contiguous ushort4.
__global__ __launch_bounds__(256) void node_mfma(
    const float* __restrict__ h,
    const unsigned short* __restrict__ whi, const unsigned short* __restrict__ wlo,
    const float* __restrict__ Wa,
    unsigned short* __restrict__ z_hb,
    unsigned short* __restrict__ u_sb, unsigned short* __restrict__ u_db,
    float* __restrict__ as_, float* __restrict__ ad_, int N)
{
    __shared__ float act[BM * 64];
    char* lds = (char*)act;
    const int lane  = threadIdx.x & 63;
    const int wave  = threadIdx.x >> 6;
    const int wrow0 = wave * 32;
    const long node0 = (long)blockIdx.x * BM;
    const int g   = lane >> 4;
    const int c15 = lane & 15;

    f32x4 acc[2][4];
    auto zacc = [&]() {
        #pragma unroll
        for (int mt = 0; mt < 2; ++mt)
            #pragma unroll
            for (int nt = 0; nt < 4; ++nt)
                #pragma unroll
                for (int rr = 0; rr < 4; ++rr) acc[mt][nt][rr] = 0.f;
    };

    auto mfma_layer = [&](int layer) {
        #pragma unroll
        for (int kt = 0; kt < 2; ++kt) {
            bf16x8 ah[2], al[2];
            #pragma unroll
            for (int mt = 0; mt < 2; ++mt) {
                f32x4 a0, a1;
                if (layer == 4) {           // A from global h
                    long nr = node0 + wrow0 + mt * 16 + c15; if (nr >= N) nr = N - 1;
                    const f32x4* p = (const f32x4*)(h + nr * 64 + kt * 32 + g * 8);
                    a0 = p[0];
                    a1 = p[1];
                } else {
                    int row = wrow0 + mt * 16 + c15;
                    int cb  = kt * 128 + g * 32;
                    a0 = *(const f32x4*)(lds + swz(row, cb));
                    a1 = *(const f32x4*)(lds + swz(row, cb + 16));
                }
                split8(a0, a1, ah[mt], al[mt]);
            }
            __builtin_amdgcn_s_setprio(1);
            #pragma unroll
            for (int nt = 0; nt < 4; ++nt) {
                int fo = ((layer * 8 + kt * 4 + nt) * 64 + lane) * 8;
                bf16x8 bh = *(const bf16x8*)(whi + fo);
                bf16x8 bl = *(const bf16x8*)(wlo + fo);
                #pragma unroll
                for (int mt = 0; mt < 2; ++mt) {
                    acc[mt][nt] = __builtin_amdgcn_mfma_f32_16x16x32_bf16(ah[mt], bh, acc[mt][nt], 0, 0, 0);
                    acc[mt][nt] = __builtin_amdgcn_mfma_f32_16x16x32_bf16(ah[mt], bl, acc[mt][nt], 0, 0, 0);
                    acc[mt][nt] = __builtin_amdgcn_mfma_f32_16x16x32_bf16(al[mt], bh, acc[mt][nt], 0, 0, 0);
                }
            }
            __builtin_amdgcn_s_setprio(0);
        }
    };

    auto writeback = [&](bool relu) {
        #pragma unroll
        for (int mt = 0; mt < 2; ++mt)
            #pragma unroll
            for (int nt = 0; nt < 4; ++nt)
                #pragma unroll
                for (int rr = 0; rr < 4; ++rr) {
                    int row  = wrow0 + mt * 16 + g * 4 + rr;
                    int colb = (nt * 16 + c15) * 4;
                    float v = acc[mt][nt][rr];
                    if (relu) v = fmaxf(v, 0.f);
                    *(float*)(lds + swz(row, colb)) = v;
                }
    };

    // fragment-major bf16 store: lane holds all 4 nt values for (node, c15)
    auto store_u = [&](unsigned short* __restrict__ out) {
        #pragma unroll
        for (int mt = 0; mt < 2; ++mt)
            #pragma unroll
            for (int rr = 0; rr < 4; ++rr) {
                long nr = node0 + wrow0 + mt * 16 + g * 4 + rr; if (nr >= N) nr = N - 1;
                ushort4 v;
                v.x = (unsigned short)f2bf_hw(acc[mt][0][rr]);
                v.y = (unsigned short)f2bf_hw(acc[mt][1][rr]);
                v.z = (unsigned short)f2bf_hw(acc[mt][2][rr]);
                v.w = (unsigned short)f2bf_hw(acc[mt][3][rr]);
                *(ushort4*)(out + nr * 64 + c15 * 4) = v;
            }
    };

    // L1: t1 = relu(h @ Wh1)
    zacc(); mfma_layer(4); writeback(true);
    // L2: z_h = t1 @ Wh2
    zacc(); mfma_layer(5);

    // as = z_h . Wa[64:128], ad = z_h . Wa[128:192]  (Wa loaded at use)
    {
        float was[4], wad[4];
        #pragma unroll
        for (int nt = 0; nt < 4; ++nt) {
            was[nt] = Wa[64  + nt * 16 + c15];
            wad[nt] = Wa[128 + nt * 16 + c15];
        }
        #pragma unroll
        for (int mt = 0; mt < 2; ++mt) {
            float ps[4], pd[4];
            #pragma unroll
            for (int rr = 0; rr < 4; ++rr) {
                ps[rr] = acc[mt][0][rr] * was[0] + acc[mt][1][rr] * was[1]
                       + acc[mt][2][rr] * was[2] + acc[mt][3][rr] * was[3];
                pd[rr] = acc[mt][0][rr] * wad[0] + acc[mt][1][rr] * wad[1]
                       + acc[mt][2][rr] * wad[2] + acc[mt][3][rr] * wad[3];
            }
            #pragma unroll
            for (int off = 1; off < 16; off <<= 1)
                #pragma unroll
                for (int rr = 0; rr < 4; ++rr) {
                    ps[rr] += __shfl_xor(ps[rr], off);
                    pd[rr] += __shfl_xor(pd[rr], off);
                }
            if (c15 == 0) {
                #pragma unroll
                for (int rr = 0; rr < 4; ++rr) {
                    long nr = node0 + wrow0 + mt * 16 + g * 4 + rr; if (nr >= N) nr = N - 1;
                    as_[nr] = ps[rr];
                    ad_[nr] = pd[rr];
                }
            }
        }
    }
    // z_h -> global as bf16 (aggregate's only consumer)
    #pragma unroll
    for (int mt = 0; mt < 2; ++mt)
        #pragma unroll
        for (int nt = 0; nt < 4; ++nt)
            #pragma unroll
            for (int rr = 0; rr < 4; ++rr) {
                long nr = node0 + wrow0 + mt * 16 + g * 4 + rr; if (nr >= N) nr = N - 1;
                z_hb[nr * 64 + nt * 16 + c15] = (unsigned short)f2bf_hw(acc[mt][nt][rr]);
            }
    writeback(false);   // z_h -> LDS for L3/L4

    // L3: u_s = z_h @ Wp1[64:128]
    zacc(); mfma_layer(6); store_u(u_sb);
    // L4: u_d = z_h @ Wp1[128:192]  (LDS still holds z_h)
    zacc(); mfma_layer(7); store_u(u_db);
}

// ---- edge pipeline (R13 schedule — the 200µs local optimum). uv gathers now
// read bf16 fragment-major rows: one ushort4 per lane per side (2 loads vs 8;
// 16-lane groups read 128B contiguous; working set 25.6->12.8MB).
__global__ __launch_bounds__(256) void edge_mfma(
    const float* __restrict__ e, const int* __restrict__ src, const int* __restrict__ dst,
    const unsigned short* __restrict__ u_sb, const unsigned short* __restrict__ u_db,
    const float* __restrict__ as_, const float* __restrict__ ad_,
    const unsigned short* __restrict__ whi, const unsigned short* __restrict__ wlo,
    const float* __restrict__ Wa, const float* __restrict__ bp1, const float* __restrict__ bp2,
    float* __restrict__ eproj, float* __restrict__ abuf, int E)
{
    __shared__ float act[BM * 64];
    char* lds = (char*)act;
    const int lane  = threadIdx.x & 63;
    const int wave  = threadIdx.x >> 6;
    const int wrow0 = wave * 32;
    const long edge0 = (long)blockIdx.x * BM;
    const int g   = lane >> 4;
    const int c15 = lane & 15;

    // (1) e-row loads FIRST — retire before the gathers (vmcnt is in-order)
    f32x4 ea[2][2][2];   // [mt][kt][half]
    #pragma unroll
    for (int mt = 0; mt < 2; ++mt) {
        long er = edge0 + wrow0 + mt * 16 + c15; if (er >= E) er = E - 1;
        #pragma unroll
        for (int kt = 0; kt < 2; ++kt) {
            const f32x4* p = (const f32x4*)(e + er * 64 + kt * 32 + g * 8);
            ea[mt][kt][0] = __builtin_nontemporal_load(p);
            ea[mt][kt][1] = __builtin_nontemporal_load(p + 1);
        }
    }

    // (2) per-edge gathers issued second — consumed at attention / L3
    float uv[2][4][4], asv[2][4];
    #pragma unroll
    for (int mt = 0; mt < 2; ++mt)
        #pragma unroll
        for (int rr = 0; rr < 4; ++rr) {
            long er = edge0 + wrow0 + mt * 16 + g * 4 + rr; if (er >= E) er = E - 1;
            int sn = src[er], dn = dst[er];
            ushort4 a = *(const ushort4*)(u_sb + (size_t)sn * 64 + c15 * 4);
            ushort4 b = *(const ushort4*)(u_db + (size_t)dn * 64 + c15 * 4);
            uv[mt][0][rr] = bf2f_hw(a.x) + bf2f_hw(b.x);
            uv[mt][1][rr] = bf2f_hw(a.y) + bf2f_hw(b.y);
            uv[mt][2][rr] = bf2f_hw(a.z) + bf2f_hw(b.z);
            uv[mt][3][rr] = bf2f_hw(a.w) + bf2f_hw(b.w);
            asv[mt][rr] = as_[sn] + ad_[dn];
        }

    f32x4 acc[2][4];
    auto zacc = [&]() {
        #pragma unroll
        for (int mt = 0; mt < 2; ++mt)
            #pragma unroll
            for (int nt = 0; nt < 4; ++nt)
                #pragma unroll
                for (int rr = 0; rr < 4; ++rr) acc[mt][nt][rr] = 0.f;
    };

    auto mfma_layer = [&](int layer) {
        #pragma unroll
        for (int kt = 0; kt < 2; ++kt) {
            bf16x8 ah[2], al[2];
            #pragma unroll
            for (int mt = 0; mt < 2; ++mt) {
                f32x4 a0, a1;
                if (layer == 0) {   // pre-loaded registers
                    a0 = ea[mt][kt][0];
                    a1 = ea[mt][kt][1];
                } else {
                    int row = wrow0 + mt * 16 + c15;
                    int cb  = kt * 128 + g * 32;
                    a0 = *(const f32x4*)(lds + swz(row, cb));
                    a1 = *(const f32x4*)(lds + swz(row, cb + 16));
                }
                split8(a0, a1, ah[mt], al[mt]);
            }
            __builtin_amdgcn_s_setprio(1);
            #pragma unroll
            for (int nt = 0; nt < 4; ++nt) {
                int fo = ((layer * 8 + kt * 4 + nt) * 64 + lane) * 8;
                bf16x8 bh = *(const bf16x8*)(whi + fo);
                bf16x8 bl = *(const bf16x8*)(wlo + fo);
                #pragma unroll
                for (int mt = 0; mt < 2; ++mt) {
                    acc[mt][nt] = __builtin_amdgcn_mfma_f32_16x16x32_bf16(ah[mt], bh, acc[mt][nt], 0, 0, 0);
                    acc[mt][nt] = __builtin_amdgcn_mfma_f32_16x16x32_bf16(ah[mt], bl, acc[mt][nt], 0, 0, 0);
                    acc[mt][nt] = __builtin_amdgcn_mfma_f32_16x16x32_bf16(al[mt], bh, acc[mt][nt], 0, 0, 0);
                }
            }
            __builtin_amdgcn_s_setprio(0);
        }
    };

    auto writeback = [&](bool relu) {
        #pragma unroll
        for (int mt = 0; mt < 2; ++mt)
            #pragma unroll
            for (int nt = 0; nt < 4; ++nt)
                #pragma unroll
                for (int rr = 0; rr < 4; ++rr) {
                    int row  = wrow0 + mt * 16 + g * 4 + rr;
                    int colb = (nt * 16 + c15) * 4;
                    float v = acc[mt][nt][rr];
                    if (relu) v = fmaxf(v, 0.f);
                    *(float*)(lds + swz(row, colb)) = v;
                }
    };

    // L1: t1 = relu(e @ We1)
    zacc(); mfma_layer(0); writeback(true);
    // L2: z_e = t1 @ We2
    zacc(); mfma_layer(1);

    // attention: ae = z_e . Wa[0:64]; a = relu(ae + as[src] + ad[dst])
    {
        float waf[4];
        #pragma unroll
        for (int nt = 0; nt < 4; ++nt) waf[nt] = Wa[nt * 16 + c15];
        #pragma unroll
        for (int mt = 0; mt < 2; ++mt) {
            float part[4];
            #pragma unroll
            for (int rr = 0; rr < 4; ++rr)
                part[rr] = acc[mt][0][rr] * waf[0] + acc[mt][1][rr] * waf[1]
                         + acc[mt][2][rr] * waf[2] + acc[mt][3][rr] * waf[3];
            #pragma unroll
            for (int off = 1; off < 16; off <<= 1)
                #pragma unroll
                for (int rr = 0; rr < 4; ++rr) part[rr] += __shfl_xor(part[rr], off);
            if (c15 == 0) {
                #pragma unroll
                for (int rr = 0; rr < 4; ++rr) {
                    long er = edge0 + wrow0 + mt * 16 + g * 4 + rr; if (er >= E) er = E - 1;
                    __builtin_nontemporal_store(fmaxf(part[rr] + asv[mt][rr], 0.f), abuf + er);
                }
            }
        }
    }
    writeback(false);

    // L3: t2 = relu(z_e @ Wp1top + uv + bp1)
    zacc(); mfma_layer(2);
    {
        float b1f[4];
        #pragma unroll
        for (int nt = 0; nt < 4; ++nt) b1f[nt] = bp1[nt * 16 + c15];
        #pragma unroll
        for (int mt = 0; mt < 2; ++mt)
            #pragma unroll
            for (int nt = 0; nt < 4; ++nt)
                #pragma unroll
                for (int rr = 0; rr < 4; ++rr)
                    acc[mt][nt][rr] += uv[mt][nt][rr] + b1f[nt];
    }
    writeback(true);

    // L4: eproj = relu(t2 @ Wp2 + bp2)  — streaming write-once: nontemporal
    zacc(); mfma_layer(3);
    {
        float b2f[4];
        #pragma unroll
        for (int nt = 0; nt < 4; ++nt) b2f[nt] = bp2[nt * 16 + c15];
        #pragma unroll
        for (int mt = 0; mt < 2; ++mt)
            #pragma unroll
            for (int nt = 0; nt < 4; ++nt)
                #pragma unroll
                for (int rr = 0; rr < 4; ++rr) {
                    long er = edge0 + wrow0 + mt * 16 + g * 4 + rr; if (er >= E) er = E - 1;
                    __builtin_nontemporal_store(fmaxf(acc[mt][nt][rr] + b2f[nt], 0.f),
                                                eproj + er * 64 + nt * 16 + c15);
                }
    }
}

// ---- CSR scan ----
__global__ __launch_bounds__(256) void k_scan1(
    const int* __restrict__ cnt, int* __restrict__ ofs, int* __restrict__ bsum, int N)
{
    __shared__ int sm[256];
    int t = threadIdx.x, i = blockIdx.x * 256 + t;
    int v = (i < N) ? cnt[i] : 0;
    sm[t] = v;
    __syncthreads();
    #pragma unroll
    for (int off = 1; off < 256; off <<= 1) {
        int tmp = (t >= off) ? sm[t - off] : 0;
        __syncthreads();
        sm[t] += tmp;
        __syncthreads();
    }
    if (i < N) ofs[i] = sm[t] - v;
    if (t == 255) bsum[blockIdx.x] = sm[255];
}

__global__ __launch_bounds__(256) void k_scan2(int* __restrict__ bsum, int NB)
{
    __shared__ int sm[256];
    int t = threadIdx.x;
    int v = (t < NB) ? bsum[t] : 0;
    sm[t] = v;
    __syncthreads();
    #pragma unroll
    for (int off = 1; off < 256; off <<= 1) {
        int tmp = (t >= off) ? sm[t - off] : 0;
        __syncthreads();
        sm[t] += tmp;
        __syncthreads();
    }
    if (t < NB) bsum[t] = sm[t] - v;   // exclusive
}

__global__ __launch_bounds__(256) void k_scan3(
    int* __restrict__ ofs, int* __restrict__ cursor,
    const int* __restrict__ bsum, int N)
{
    int i = blockIdx.x * 256 + threadIdx.x;
    if (i < N) {
        int o = ofs[i] + bsum[blockIdx.x];
        ofs[i] = o;
        cursor[i] = o;
    }
}

// fill packs (edge id, src node) so aggregate has one fewer dependent gather
__global__ __launch_bounds__(256) void k_fill(
    const int* __restrict__ dst, const int* __restrict__ src,
    int* __restrict__ cursor, int2* __restrict__ esrc, int E)
{
    int i = blockIdx.x * 256 + threadIdx.x;
    if (i < E) {
        int p = atomicAdd(&cursor[dst[i]], 1);
        esrc[p] = make_int2(i, src[i]);
    }
}

// ---- fused segment softmax + weighted gather: 1 wave/node.
// z_h gathered as bf16 (ushort4, 8B/lane) — half the random-read bytes.
__global__ __launch_bounds__(256) void k_aggregate(
    const float* __restrict__ abuf, const int2* __restrict__ esrc,
    const int* __restrict__ ofs, const int* __restrict__ cnt,
    const unsigned short* __restrict__ z_hb, float* __restrict__ hout, int N)
{
    int wid  = (blockIdx.x * 256 + threadIdx.x) >> 6;
    int lane = threadIdx.x & 63;
    if (wid >= N) return;
    int grp = lane >> 4, c15 = lane & 15;

    int begin = ofs[wid];
    int deg   = cnt[wid];

    float4 acc = make_float4(0.f, 0.f, 0.f, 0.f);
    float inv_s;

    if (deg <= 64) {
        float a = 0.f; int sidx = 0;
        if (lane < deg) {
            int2 es = esrc[begin + lane];
            a    = abuf[es.x];
            sidx = es.y;
        }
        float m = a;
        #pragma unroll
        for (int off = 32; off; off >>= 1) m = fmaxf(m, __shfl_xor(m, off));

        float ex = (lane < deg) ? __expf(a - m) : 0.f;
        float s = ex;
        #pragma unroll
        for (int off = 32; off; off >>= 1) s += __shfl_xor(s, off);
        inv_s = 1.0f / fmaxf(s, 1e-9f);

        int trips = (deg + 3) >> 2;
        for (int i = 0; i < trips; ++i) {
            int k = grp + 4 * i;
            float w  = __shfl(ex,   k & 63);
            int   sk = __shfl(sidx, k & 63);
            if (k < deg) {
                const ushort4 v = *(const ushort4*)(z_hb + (size_t)sk * DIM + c15 * 4);
                acc.x = fmaf(w, bf2f_hw(v.x), acc.x);
                acc.y = fmaf(w, bf2f_hw(v.y), acc.y);
                acc.z = fmaf(w, bf2f_hw(v.z), acc.z);
                acc.w = fmaf(w, bf2f_hw(v.w), acc.w);
            }
        }
    } else {
        float m = 0.f;
        for (int k = lane; k < deg; k += 64) m = fmaxf(m, abuf[esrc[begin + k].x]);
        #pragma unroll
        for (int off = 32; off; off >>= 1) m = fmaxf(m, __shfl_xor(m, off));

        float s = 0.f;
        for (int k = lane; k < deg; k += 64) s += __expf(abuf[esrc[begin + k].x] - m);
        #pragma unroll
        for (int off = 32; off; off >>= 1) s += __shfl_xor(s, off);
        inv_s = 1.0f / fmaxf(s, 1e-9f);

        for (int k = grp; k < deg; k += 4) {
            int2 es = esrc[begin + k];
            float w = __expf(abuf[es.x] - m);
            const ushort4 v = *(const ushort4*)(z_hb + (size_t)es.y * DIM + c15 * 4);
            acc.x = fmaf(w, bf2f_hw(v.x), acc.x);
            acc.y = fmaf(w, bf2f_hw(v.y), acc.y);
            acc.z = fmaf(w, bf2f_hw(v.z), acc.z);
            acc.w = fmaf(w, bf2f_hw(v.w), acc.w);
        }
    }

    #pragma unroll
    for (int off = 16; off <= 32; off <<= 1) {
        acc.x += __shfl_xor(acc.x, off);
        acc.y += __shfl_xor(acc.y, off);
        acc.z += __shfl_xor(acc.z, off);
        acc.w += __shfl_xor(acc.w, off);
    }
    if (grp == 0) {
        float4 r = make_float4(fmaxf(acc.x * inv_s, 0.f), fmaxf(acc.y * inv_s, 0.f),
                               fmaxf(acc.z * inv_s, 0.f), fmaxf(acc.w * inv_s, 0.f));
        *(float4*)(hout + (size_t)wid * DIM + c15 * 4) = r;
    }
}

extern "C" void kernel_launch(void* const* d_in, const int* in_sizes, int n_in,
                              void* d_out, int out_size, void* d_ws, size_t ws_size,
                              hipStream_t stream)
{
    const float* h   = (const float*)d_in[0];
    const float* e   = (const float*)d_in[1];
    const int*   src = (const int*)d_in[2];
    const int*   dst = (const int*)d_in[3];
    const float* Wh1 = (const float*)d_in[4];
    const float* Wh2 = (const float*)d_in[5];
    const float* We1 = (const float*)d_in[6];
    const float* We2 = (const float*)d_in[7];
    const float* Wp1 = (const float*)d_in[8];
    const float* bp1 = (const float*)d_in[9];
    const float* Wp2 = (const float*)d_in[10];
    const float* bp2 = (const float*)d_in[11];
    const float* Wa  = (const float*)d_in[12];

    const int N = in_sizes[0] / DIM;
    const int E = in_sizes[1] / DIM;

    float* ws   = (float*)d_ws;
    unsigned short* z_hb = (unsigned short*)ws;  ws += (size_t)N * DIM / 2;
    unsigned short* u_sb = (unsigned short*)ws;  ws += (size_t)N * DIM / 2;
    unsigned short* u_db = (unsigned short*)ws;  ws += (size_t)N * DIM / 2;
    float* as_  = ws;  ws += N;
    float* ad_  = ws;  ws += N;
    float* abuf = ws;  ws += E;
    int* cnt    = (int*)ws;  ws += N;
    int* ofs    = (int*)ws;  ws += N;
    int* cursor = (int*)ws;  ws += N;
    int2* esrc  = (int2*)ws; ws += (size_t)2 * E;
    int* bsum   = (int*)ws;  ws += 256;
    unsigned short* whi = (unsigned short*)ws;  ws += 32768 / 2;
    unsigned short* wlo = (unsigned short*)ws;  ws += 32768 / 2;

    float* hout  = (float*)d_out;
    float* eproj = hout + (size_t)N * DIM;

    const int NB = (N + 255) / 256;   // N=50000 -> 196 <= 256

    hipMemsetAsync(cnt, 0, (size_t)N * sizeof(int), stream);

    k_prep_hist<<<(E + 255) / 256, 256, 0, stream>>>(
        We1, We2, Wp1, Wp2, Wh1, Wh2, whi, wlo, dst, cnt, E);

    k_scan1<<<NB, 256, 0, stream>>>(cnt, ofs, bsum, N);
    k_scan2<<<1, 256, 0, stream>>>(bsum, NB);
    k_scan3<<<NB, 256, 0, stream>>>(ofs, cursor, bsum, N);
    k_fill<<<(E + 255) / 256, 256, 0, stream>>>(dst, src, cursor, esrc, E);

    node_mfma<<<(N + BM - 1) / BM, 256, 0, stream>>>(
        h, whi, wlo, Wa, z_hb, u_sb, u_db, as_, ad_, N);

    edge_mfma<<<(E + BM - 1) / BM, 256, 0, stream>>>(
        e, src, dst, u_sb, u_db, as_, ad_, whi, wlo, Wa, bp1, bp2,
        eproj, abuf, E);

    k_aggregate<<<((N * 64) + 255) / 256, 256, 0, stream>>>(
        abuf, esrc, ofs, cnt, z_hb, hout, N);
}

// Round 17
// 311.835 us; speedup vs baseline: 1.1791x; 1.0043x over previous
//
#include <hip/hip_runtime.h>
#include <hip/hip_bf16.h>

#define DIM 64
#define BM 128

typedef __attribute__((ext_vector_type(8))) short bf16x8;
typedef __attribute__((ext_vector_type(4))) float f32x4;

__device__ __forceinline__ short f2bf_hw(float x) {
    __hip_bfloat16 b = __float2bfloat16(x);
    return (short)reinterpret_cast<unsigned short&>(b);
}
__device__ __forceinline__ float bf2f_hw(unsigned short s) {
    return __uint_as_float(((unsigned)s) << 16);
}
// full split: hi+lo (3-term MFMA — R12 showed 2-term is SLOWER; MFMAs are free)
__device__ __forceinline__ void split8(f32x4 a, f32x4 b, bf16x8& hi, bf16x8& lo) {
    float v[8] = {a[0], a[1], a[2], a[3], b[0], b[1], b[2], b[3]};
    #pragma unroll
    for (int i = 0; i < 8; ++i) {
        short h = f2bf_hw(v[i]);
        hi[i] = h;
        lo[i] = f2bf_hw(v[i] - bf2f_hw((unsigned short)h));
    }
}
// XOR-swizzle (T2): byte address within act tile; row stride 256B
__device__ __forceinline__ int swz(int row, int colbyte) {
    return row * 256 + (colbyte ^ ((row & 7) << 4));
}

// ---- weight prep (first 128 blocks) + dst histogram + (src,dst) int2 pack
__global__ __launch_bounds__(256) void k_prep_hist(
    const float* __restrict__ We1, const float* __restrict__ We2,
    const float* __restrict__ Wp1, const float* __restrict__ Wp2,
    const float* __restrict__ Wh1, const float* __restrict__ Wh2,
    unsigned short* __restrict__ whi, unsigned short* __restrict__ wlo,
    const int* __restrict__ src, const int* __restrict__ dst,
    int* __restrict__ cnt, int2* __restrict__ sd, int E)
{
    int t = blockIdx.x * 256 + threadIdx.x;
    if (t < 32768) {
        int e_ = t & 7, lane = (t >> 3) & 63, frag = (t >> 9) & 7, layer = t >> 12;
        int kt = frag >> 2, nt = frag & 3;
        int k = kt * 32 + ((lane >> 4) * 8) + e_;
        int n = nt * 16 + (lane & 15);
        const float* W;
        switch (layer) {
            case 0: W = We1; break;
            case 1: W = We2; break;
            case 2: W = Wp1; break;
            case 3: W = Wp2; break;
            case 4: W = Wh1; break;
            case 5: W = Wh2; break;
            case 6: W = Wp1 + 64 * 64; break;
            default: W = Wp1 + 128 * 64; break;
        }
        float w = W[k * 64 + n];
        short h = f2bf_hw(w);
        whi[t] = (unsigned short)h;
        wlo[t] = (unsigned short)f2bf_hw(w - bf2f_hw((unsigned short)h));
    }
    for (int i = t; i < E; i += gridDim.x * 256) {
        int d = dst[i];
        atomicAdd(&cnt[d], 1);
        sd[i] = make_int2(src[i], d);
    }
}

// ---- node pipeline via MFMA + CSR-fill tail (grid-stride over E; cursor must
// be ready at launch — scans run before). z_h/u_s/u_d stored bf16; u uses
// fragment-major [node][c15][nt] so edge's per-lane gather is one ushort4.
__global__ __launch_bounds__(256) void node_mfma(
    const float* __restrict__ h,
    const unsigned short* __restrict__ whi, const unsigned short* __restrict__ wlo,
    const float* __restrict__ Wa,
    unsigned short* __restrict__ z_hb,
    unsigned short* __restrict__ u_sb, unsigned short* __restrict__ u_db,
    float* __restrict__ as_, float* __restrict__ ad_,
    const int2* __restrict__ sd, int* __restrict__ cursor, int2* __restrict__ esrc,
    int N, int E)
{
    __shared__ float act[BM * 64];
    char* lds = (char*)act;
    const int lane  = threadIdx.x & 63;
    const int wave  = threadIdx.x >> 6;
    const int wrow0 = wave * 32;
    const long node0 = (long)blockIdx.x * BM;
    const int g   = lane >> 4;
    const int c15 = lane & 15;

    f32x4 acc[2][4];
    auto zacc = [&]() {
        #pragma unroll
        for (int mt = 0; mt < 2; ++mt)
            #pragma unroll
            for (int nt = 0; nt < 4; ++nt)
                #pragma unroll
                for (int rr = 0; rr < 4; ++rr) acc[mt][nt][rr] = 0.f;
    };

    auto mfma_layer = [&](int layer) {
        #pragma unroll
        for (int kt = 0; kt < 2; ++kt) {
            bf16x8 ah[2], al[2];
            #pragma unroll
            for (int mt = 0; mt < 2; ++mt) {
                f32x4 a0, a1;
                if (layer == 4) {           // A from global h
                    long nr = node0 + wrow0 + mt * 16 + c15; if (nr >= N) nr = N - 1;
                    const f32x4* p = (const f32x4*)(h + nr * 64 + kt * 32 + g * 8);
                    a0 = p[0];
                    a1 = p[1];
                } else {
                    int row = wrow0 + mt * 16 + c15;
                    int cb  = kt * 128 + g * 32;
                    a0 = *(const f32x4*)(lds + swz(row, cb));
                    a1 = *(const f32x4*)(lds + swz(row, cb + 16));
                }
                split8(a0, a1, ah[mt], al[mt]);
            }
            __builtin_amdgcn_s_setprio(1);
            #pragma unroll
            for (int nt = 0; nt < 4; ++nt) {
                int fo = ((layer * 8 + kt * 4 + nt) * 64 + lane) * 8;
                bf16x8 bh = *(const bf16x8*)(whi + fo);
                bf16x8 bl = *(const bf16x8*)(wlo + fo);
                #pragma unroll
                for (int mt = 0; mt < 2; ++mt) {
                    acc[mt][nt] = __builtin_amdgcn_mfma_f32_16x16x32_bf16(ah[mt], bh, acc[mt][nt], 0, 0, 0);
                    acc[mt][nt] = __builtin_amdgcn_mfma_f32_16x16x32_bf16(ah[mt], bl, acc[mt][nt], 0, 0, 0);
                    acc[mt][nt] = __builtin_amdgcn_mfma_f32_16x16x32_bf16(al[mt], bh, acc[mt][nt], 0, 0, 0);
                }
            }
            __builtin_amdgcn_s_setprio(0);
        }
    };

    auto writeback = [&](bool relu) {
        #pragma unroll
        for (int mt = 0; mt < 2; ++mt)
            #pragma unroll
            for (int nt = 0; nt < 4; ++nt)
                #pragma unroll
                for (int rr = 0; rr < 4; ++rr) {
                    int row  = wrow0 + mt * 16 + g * 4 + rr;
                    int colb = (nt * 16 + c15) * 4;
                    float v = acc[mt][nt][rr];
                    if (relu) v = fmaxf(v, 0.f);
                    *(float*)(lds + swz(row, colb)) = v;
                }
    };

    // fragment-major bf16 store: lane holds all 4 nt values for (node, c15)
    auto store_u = [&](unsigned short* __restrict__ out) {
        #pragma unroll
        for (int mt = 0; mt < 2; ++mt)
            #pragma unroll
            for (int rr = 0; rr < 4; ++rr) {
                long nr = node0 + wrow0 + mt * 16 + g * 4 + rr; if (nr >= N) nr = N - 1;
                ushort4 v;
                v.x = (unsigned short)f2bf_hw(acc[mt][0][rr]);
                v.y = (unsigned short)f2bf_hw(acc[mt][1][rr]);
                v.z = (unsigned short)f2bf_hw(acc[mt][2][rr]);
                v.w = (unsigned short)f2bf_hw(acc[mt][3][rr]);
                *(ushort4*)(out + nr * 64 + c15 * 4) = v;
            }
    };

    // L1: t1 = relu(h @ Wh1)
    zacc(); mfma_layer(4); writeback(true);
    // L2: z_h = t1 @ Wh2
    zacc(); mfma_layer(5);

    // as = z_h . Wa[64:128], ad = z_h . Wa[128:192]  (Wa loaded at use)
    {
        float was[4], wad[4];
        #pragma unroll
        for (int nt = 0; nt < 4; ++nt) {
            was[nt] = Wa[64  + nt * 16 + c15];
            wad[nt] = Wa[128 + nt * 16 + c15];
        }
        #pragma unroll
        for (int mt = 0; mt < 2; ++mt) {
            float ps[4], pd[4];
            #pragma unroll
            for (int rr = 0; rr < 4; ++rr) {
                ps[rr] = acc[mt][0][rr] * was[0] + acc[mt][1][rr] * was[1]
                       + acc[mt][2][rr] * was[2] + acc[mt][3][rr] * was[3];
                pd[rr] = acc[mt][0][rr] * wad[0] + acc[mt][1][rr] * wad[1]
                       + acc[mt][2][rr] * wad[2] + acc[mt][3][rr] * wad[3];
            }
            #pragma unroll
            for (int off = 1; off < 16; off <<= 1)
                #pragma unroll
                for (int rr = 0; rr < 4; ++rr) {
                    ps[rr] += __shfl_xor(ps[rr], off);
                    pd[rr] += __shfl_xor(pd[rr], off);
                }
            if (c15 == 0) {
                #pragma unroll
                for (int rr = 0; rr < 4; ++rr) {
                    long nr = node0 + wrow0 + mt * 16 + g * 4 + rr; if (nr >= N) nr = N - 1;
                    as_[nr] = ps[rr];
                    ad_[nr] = pd[rr];
                }
            }
        }
    }
    // z_h -> global as bf16 (aggregate's only consumer)
    #pragma unroll
    for (int mt = 0; mt < 2; ++mt)
        #pragma unroll
        for (int nt = 0; nt < 4; ++nt)
            #pragma unroll
            for (int rr = 0; rr < 4; ++rr) {
                long nr = node0 + wrow0 + mt * 16 + g * 4 + rr; if (nr >= N) nr = N - 1;
                z_hb[nr * 64 + nt * 16 + c15] = (unsigned short)f2bf_hw(acc[mt][nt][rr]);
            }
    writeback(false);   // z_h -> LDS for L3/L4

    // L3: u_s = z_h @ Wp1[64:128]
    zacc(); mfma_layer(6); store_u(u_sb);
    // L4: u_d = z_h @ Wp1[128:192]  (LDS still holds z_h)
    zacc(); mfma_layer(7); store_u(u_db);

    // ---- CSR fill tail (was a standalone 28µs kernel): atomics overlap with
    // other blocks' MFMA compute since blocks reach here at staggered times.
    {
        int tid = blockIdx.x * 256 + threadIdx.x;
        int stride = gridDim.x * 256;
        for (int i = tid; i < E; i += stride) {
            int2 v = sd[i];
            int p = atomicAdd(&cursor[v.y], 1);
            esrc[p] = make_int2(i, v.x);
        }
    }
}

// ---- edge pipeline (R13 schedule — the local optimum). Head gathers read
// packed sd (int2) + fragment-major bf16 u rows (one ushort4 per lane/side).
__global__ __launch_bounds__(256) void edge_mfma(
    const float* __restrict__ e, const int2* __restrict__ sd,
    const unsigned short* __restrict__ u_sb, const unsigned short* __restrict__ u_db,
    const float* __restrict__ as_, const float* __restrict__ ad_,
    const unsigned short* __restrict__ whi, const unsigned short* __restrict__ wlo,
    const float* __restrict__ Wa, const float* __restrict__ bp1, const float* __restrict__ bp2,
    float* __restrict__ eproj, float* __restrict__ abuf, int E)
{
    __shared__ float act[BM * 64];
    char* lds = (char*)act;
    const int lane  = threadIdx.x & 63;
    const int wave  = threadIdx.x >> 6;
    const int wrow0 = wave * 32;
    const long edge0 = (long)blockIdx.x * BM;
    const int g   = lane >> 4;
    const int c15 = lane & 15;

    // (1) e-row loads FIRST — retire before the gathers (vmcnt is in-order)
    f32x4 ea[2][2][2];   // [mt][kt][half]
    #pragma unroll
    for (int mt = 0; mt < 2; ++mt) {
        long er = edge0 + wrow0 + mt * 16 + c15; if (er >= E) er = E - 1;
        #pragma unroll
        for (int kt = 0; kt < 2; ++kt) {
            const f32x4* p = (const f32x4*)(e + er * 64 + kt * 32 + g * 8);
            ea[mt][kt][0] = __builtin_nontemporal_load(p);
            ea[mt][kt][1] = __builtin_nontemporal_load(p + 1);
        }
    }

    // (2) per-edge gathers issued second — consumed at attention / L3
    float uv[2][4][4], asv[2][4];
    #pragma unroll
    for (int mt = 0; mt < 2; ++mt)
        #pragma unroll
        for (int rr = 0; rr < 4; ++rr) {
            long er = edge0 + wrow0 + mt * 16 + g * 4 + rr; if (er >= E) er = E - 1;
            int2 sdv = sd[er];
            int sn = sdv.x, dn = sdv.y;
            ushort4 a = *(const ushort4*)(u_sb + (size_t)sn * 64 + c15 * 4);
            ushort4 b = *(const ushort4*)(u_db + (size_t)dn * 64 + c15 * 4);
            uv[mt][0][rr] = bf2f_hw(a.x) + bf2f_hw(b.x);
            uv[mt][1][rr] = bf2f_hw(a.y) + bf2f_hw(b.y);
            uv[mt][2][rr] = bf2f_hw(a.z) + bf2f_hw(b.z);
            uv[mt][3][rr] = bf2f_hw(a.w) + bf2f_hw(b.w);
            asv[mt][rr] = as_[sn] + ad_[dn];
        }

    f32x4 acc[2][4];
    auto zacc = [&]() {
        #pragma unroll
        for (int mt = 0; mt < 2; ++mt)
            #pragma unroll
            for (int nt = 0; nt < 4; ++nt)
                #pragma unroll
                for (int rr = 0; rr < 4; ++rr) acc[mt][nt][rr] = 0.f;
    };

    auto mfma_layer = [&](int layer) {
        #pragma unroll
        for (int kt = 0; kt < 2; ++kt) {
            bf16x8 ah[2], al[2];
            #pragma unroll
            for (int mt = 0; mt < 2; ++mt) {
                f32x4 a0, a1;
                if (layer == 0) {   // pre-loaded registers
                    a0 = ea[mt][kt][0];
                    a1 = ea[mt][kt][1];
                } else {
                    int row = wrow0 + mt * 16 + c15;
                    int cb  = kt * 128 + g * 32;
                    a0 = *(const f32x4*)(lds + swz(row, cb));
                    a1 = *(const f32x4*)(lds + swz(row, cb + 16));
                }
                split8(a0, a1, ah[mt], al[mt]);
            }
            __builtin_amdgcn_s_setprio(1);
            #pragma unroll
            for (int nt = 0; nt < 4; ++nt) {
                int fo = ((layer * 8 + kt * 4 + nt) * 64 + lane) * 8;
                bf16x8 bh = *(const bf16x8*)(whi + fo);
                bf16x8 bl = *(const bf16x8*)(wlo + fo);
                #pragma unroll
                for (int mt = 0; mt < 2; ++mt) {
                    acc[mt][nt] = __builtin_amdgcn_mfma_f32_16x16x32_bf16(ah[mt], bh, acc[mt][nt], 0, 0, 0);
                    acc[mt][nt] = __builtin_amdgcn_mfma_f32_16x16x32_bf16(ah[mt], bl, acc[mt][nt], 0, 0, 0);
                    acc[mt][nt] = __builtin_amdgcn_mfma_f32_16x16x32_bf16(al[mt], bh, acc[mt][nt], 0, 0, 0);
                }
            }
            __builtin_amdgcn_s_setprio(0);
        }
    };

    auto writeback = [&](bool relu) {
        #pragma unroll
        for (int mt = 0; mt < 2; ++mt)
            #pragma unroll
            for (int nt = 0; nt < 4; ++nt)
                #pragma unroll
                for (int rr = 0; rr < 4; ++rr) {
                    int row  = wrow0 + mt * 16 + g * 4 + rr;
                    int colb = (nt * 16 + c15) * 4;
                    float v = acc[mt][nt][rr];
                    if (relu) v = fmaxf(v, 0.f);
                    *(float*)(lds + swz(row, colb)) = v;
                }
    };

    // L1: t1 = relu(e @ We1)
    zacc(); mfma_layer(0); writeback(true);
    // L2: z_e = t1 @ We2
    zacc(); mfma_layer(1);

    // attention: ae = z_e . Wa[0:64]; a = relu(ae + as[src] + ad[dst])
    {
        float waf[4];
        #pragma unroll
        for (int nt = 0; nt < 4; ++nt) waf[nt] = Wa[nt * 16 + c15];
        #pragma unroll
        for (int mt = 0; mt < 2; ++mt) {
            float part[4];
            #pragma unroll
            for (int rr = 0; rr < 4; ++rr)
                part[rr] = acc[mt][0][rr] * waf[0] + acc[mt][1][rr] * waf[1]
                         + acc[mt][2][rr] * waf[2] + acc[mt][3][rr] * waf[3];
            #pragma unroll
            for (int off = 1; off < 16; off <<= 1)
                #pragma unroll
                for (int rr = 0; rr < 4; ++rr) part[rr] += __shfl_xor(part[rr], off);
            if (c15 == 0) {
                #pragma unroll
                for (int rr = 0; rr < 4; ++rr) {
                    long er = edge0 + wrow0 + mt * 16 + g * 4 + rr; if (er >= E) er = E - 1;
                    __builtin_nontemporal_store(fmaxf(part[rr] + asv[mt][rr], 0.f), abuf + er);
                }
            }
        }
    }
    writeback(false);

    // L3: t2 = relu(z_e @ Wp1top + uv + bp1)
    zacc(); mfma_layer(2);
    {
        float b1f[4];
        #pragma unroll
        for (int nt = 0; nt < 4; ++nt) b1f[nt] = bp1[nt * 16 + c15];
        #pragma unroll
        for (int mt = 0; mt < 2; ++mt)
            #pragma unroll
            for (int nt = 0; nt < 4; ++nt)
                #pragma unroll
                for (int rr = 0; rr < 4; ++rr)
                    acc[mt][nt][rr] += uv[mt][nt][rr] + b1f[nt];
    }
    writeback(true);

    // L4: eproj = relu(t2 @ Wp2 + bp2)  — streaming write-once: nontemporal
    zacc(); mfma_layer(3);
    {
        float b2f[4];
        #pragma unroll
        for (int nt = 0; nt < 4; ++nt) b2f[nt] = bp2[nt * 16 + c15];
        #pragma unroll
        for (int mt = 0; mt < 2; ++mt)
            #pragma unroll
            for (int nt = 0; nt < 4; ++nt)
                #pragma unroll
                for (int rr = 0; rr < 4; ++rr) {
                    long er = edge0 + wrow0 + mt * 16 + g * 4 + rr; if (er >= E) er = E - 1;
                    __builtin_nontemporal_store(fmaxf(acc[mt][nt][rr] + b2f[nt], 0.f),
                                                eproj + er * 64 + nt * 16 + c15);
                }
    }
}

// ---- CSR scan ----
__global__ __launch_bounds__(256) void k_scan1(
    const int* __restrict__ cnt, int* __restrict__ ofs, int* __restrict__ bsum, int N)
{
    __shared__ int sm[256];
    int t = threadIdx.x, i = blockIdx.x * 256 + t;
    int v = (i < N) ? cnt[i] : 0;
    sm[t] = v;
    __syncthreads();
    #pragma unroll
    for (int off = 1; off < 256; off <<= 1) {
        int tmp = (t >= off) ? sm[t - off] : 0;
        __syncthreads();
        sm[t] += tmp;
        __syncthreads();
    }
    if (i < N) ofs[i] = sm[t] - v;
    if (t == 255) bsum[blockIdx.x] = sm[255];
}

__global__ __launch_bounds__(256) void k_scan2(int* __restrict__ bsum, int NB)
{
    __shared__ int sm[256];
    int t = threadIdx.x;
    int v = (t < NB) ? bsum[t] : 0;
    sm[t] = v;
    __syncthreads();
    #pragma unroll
    for (int off = 1; off < 256; off <<= 1) {
        int tmp = (t >= off) ? sm[t - off] : 0;
        __syncthreads();
        sm[t] += tmp;
        __syncthreads();
    }
    if (t < NB) bsum[t] = sm[t] - v;   // exclusive
}

__global__ __launch_bounds__(256) void k_scan3(
    int* __restrict__ ofs, int* __restrict__ cursor,
    const int* __restrict__ bsum, int N)
{
    int i = blockIdx.x * 256 + threadIdx.x;
    if (i < N) {
        int o = ofs[i] + bsum[blockIdx.x];
        ofs[i] = o;
        cursor[i] = o;
    }
}

// ---- fused segment softmax + weighted gather: 1 wave/node.
// z_h gathered as bf16 (ushort4, 8B/lane) — half the random-read bytes.
__global__ __launch_bounds__(256) void k_aggregate(
    const float* __restrict__ abuf, const int2* __restrict__ esrc,
    const int* __restrict__ ofs, const int* __restrict__ cnt,
    const unsigned short* __restrict__ z_hb, float* __restrict__ hout, int N)
{
    int wid  = (blockIdx.x * 256 + threadIdx.x) >> 6;
    int lane = threadIdx.x & 63;
    if (wid >= N) return;
    int grp = lane >> 4, c15 = lane & 15;

    int begin = ofs[wid];
    int deg   = cnt[wid];

    float4 acc = make_float4(0.f, 0.f, 0.f, 0.f);
    float inv_s;

    if (deg <= 64) {
        float a = 0.f; int sidx = 0;
        if (lane < deg) {
            int2 es = esrc[begin + lane];
            a    = abuf[es.x];
            sidx = es.y;
        }
        float m = a;
        #pragma unroll
        for (int off = 32; off; off >>= 1) m = fmaxf(m, __shfl_xor(m, off));

        float ex = (lane < deg) ? __expf(a - m) : 0.f;
        float s = ex;
        #pragma unroll
        for (int off = 32; off; off >>= 1) s += __shfl_xor(s, off);
        inv_s = 1.0f / fmaxf(s, 1e-9f);

        int trips = (deg + 3) >> 2;
        for (int i = 0; i < trips; ++i) {
            int k = grp + 4 * i;
            float w  = __shfl(ex,   k & 63);
            int   sk = __shfl(sidx, k & 63);
            if (k < deg) {
                const ushort4 v = *(const ushort4*)(z_hb + (size_t)sk * DIM + c15 * 4);
                acc.x = fmaf(w, bf2f_hw(v.x), acc.x);
                acc.y = fmaf(w, bf2f_hw(v.y), acc.y);
                acc.z = fmaf(w, bf2f_hw(v.z), acc.z);
                acc.w = fmaf(w, bf2f_hw(v.w), acc.w);
            }
        }
    } else {
        float m = 0.f;
        for (int k = lane; k < deg; k += 64) m = fmaxf(m, abuf[esrc[begin + k].x]);
        #pragma unroll
        for (int off = 32; off; off >>= 1) m = fmaxf(m, __shfl_xor(m, off));

        float s = 0.f;
        for (int k = lane; k < deg; k += 64) s += __expf(abuf[esrc[begin + k].x] - m);
        #pragma unroll
        for (int off = 32; off; off >>= 1) s += __shfl_xor(s, off);
        inv_s = 1.0f / fmaxf(s, 1e-9f);

        for (int k = grp; k < deg; k += 4) {
            int2 es = esrc[begin + k];
            float w = __expf(abuf[es.x] - m);
            const ushort4 v = *(const ushort4*)(z_hb + (size_t)es.y * DIM + c15 * 4);
            acc.x = fmaf(w, bf2f_hw(v.x), acc.x);
            acc.y = fmaf(w, bf2f_hw(v.y), acc.y);
            acc.z = fmaf(w, bf2f_hw(v.z), acc.z);
            acc.w = fmaf(w, bf2f_hw(v.w), acc.w);
        }
    }

    #pragma unroll
    for (int off = 16; off <= 32; off <<= 1) {
        acc.x += __shfl_xor(acc.x, off);
        acc.y += __shfl_xor(acc.y, off);
        acc.z += __shfl_xor(acc.z, off);
        acc.w += __shfl_xor(acc.w, off);
    }
    if (grp == 0) {
        float4 r = make_float4(fmaxf(acc.x * inv_s, 0.f), fmaxf(acc.y * inv_s, 0.f),
                               fmaxf(acc.z * inv_s, 0.f), fmaxf(acc.w * inv_s, 0.f));
        *(float4*)(hout + (size_t)wid * DIM + c15 * 4) = r;
    }
}

extern "C" void kernel_launch(void* const* d_in, const int* in_sizes, int n_in,
                              void* d_out, int out_size, void* d_ws, size_t ws_size,
                              hipStream_t stream)
{
    const float* h   = (const float*)d_in[0];
    const float* e   = (const float*)d_in[1];
    const int*   src = (const int*)d_in[2];
    const int*   dst = (const int*)d_in[3];
    const float* Wh1 = (const float*)d_in[4];
    const float* Wh2 = (const float*)d_in[5];
    const float* We1 = (const float*)d_in[6];
    const float* We2 = (const float*)d_in[7];
    const float* Wp1 = (const float*)d_in[8];
    const float* bp1 = (const float*)d_in[9];
    const float* Wp2 = (const float*)d_in[10];
    const float* bp2 = (const float*)d_in[11];
    const float* Wa  = (const float*)d_in[12];

    const int N = in_sizes[0] / DIM;
    const int E = in_sizes[1] / DIM;

    float* ws   = (float*)d_ws;
    unsigned short* z_hb = (unsigned short*)ws;  ws += (size_t)N * DIM / 2;
    unsigned short* u_sb = (unsigned short*)ws;  ws += (size_t)N * DIM / 2;
    unsigned short* u_db = (unsigned short*)ws;  ws += (size_t)N * DIM / 2;
    float* as_  = ws;  ws += N;
    float* ad_  = ws;  ws += N;
    float* abuf = ws;  ws += E;
    int* cnt    = (int*)ws;  ws += N;
    int* ofs    = (int*)ws;  ws += N;
    int* cursor = (int*)ws;  ws += N;
    int2* esrc  = (int2*)ws; ws += (size_t)2 * E;
    int2* sd    = (int2*)ws; ws += (size_t)2 * E;
    int* bsum   = (int*)ws;  ws += 256;
    unsigned short* whi = (unsigned short*)ws;  ws += 32768 / 2;
    unsigned short* wlo = (unsigned short*)ws;  ws += 32768 / 2;

    float* hout  = (float*)d_out;
    float* eproj = hout + (size_t)N * DIM;

    const int NB = (N + 255) / 256;   // N=50000 -> 196 <= 256

    hipMemsetAsync(cnt, 0, (size_t)N * sizeof(int), stream);

    k_prep_hist<<<(E + 255) / 256, 256, 0, stream>>>(
        We1, We2, Wp1, Wp2, Wh1, Wh2, whi, wlo, src, dst, cnt, sd, E);

    k_scan1<<<NB, 256, 0, stream>>>(cnt, ofs, bsum, N);
    k_scan2<<<1, 256, 0, stream>>>(bsum, NB);
    k_scan3<<<NB, 256, 0, stream>>>(ofs, cursor, bsum, N);

    node_mfma<<<(N + BM - 1) / BM, 256, 0, stream>>>(
        h, whi, wlo, Wa, z_hb, u_sb, u_db, as_, ad_, sd, cursor, esrc, N, E);

    edge_mfma<<<(E + BM - 1) / BM, 256, 0, stream>>>(
        e, sd, u_sb, u_db, as_, ad_, whi, wlo, Wa, bp1, bp2,
        eproj, abuf, E);

    k_aggregate<<<((N * 64) + 255) / 256, 256, 0, stream>>>(
        abuf, esrc, ofs, cnt, z_hb, hout, N);
}

// Round 18
// 306.913 us; speedup vs baseline: 1.1981x; 1.0160x over previous
//
#include <hip/hip_runtime.h>
#include <hip/hip_bf16.h>

#define DIM 64
#define BM 128

typedef __attribute__((ext_vector_type(8))) short bf16x8;
typedef __attribute__((ext_vector_type(4))) float f32x4;

__device__ __forceinline__ short f2bf_hw(float x) {
    __hip_bfloat16 b = __float2bfloat16(x);
    return (short)reinterpret_cast<unsigned short&>(b);
}
__device__ __forceinline__ float bf2f_hw(unsigned short s) {
    return __uint_as_float(((unsigned)s) << 16);
}
// full split: hi+lo (3-term MFMA — R12 showed 2-term is SLOWER; MFMAs are free)
__device__ __forceinline__ void split8(f32x4 a, f32x4 b, bf16x8& hi, bf16x8& lo) {
    float v[8] = {a[0], a[1], a[2], a[3], b[0], b[1], b[2], b[3]};
    #pragma unroll
    for (int i = 0; i < 8; ++i) {
        short h = f2bf_hw(v[i]);
        hi[i] = h;
        lo[i] = f2bf_hw(v[i] - bf2f_hw((unsigned short)h));
    }
}
// XOR-swizzle (T2): byte address within act tile; row stride 256B
__device__ __forceinline__ int swz(int row, int colbyte) {
    return row * 256 + (colbyte ^ ((row & 7) << 4));
}

// ---- weight prep (first 128 blocks) + dst histogram + (src,dst) int2 pack
__global__ __launch_bounds__(256) void k_prep_hist(
    const float* __restrict__ We1, const float* __restrict__ We2,
    const float* __restrict__ Wp1, const float* __restrict__ Wp2,
    const float* __restrict__ Wh1, const float* __restrict__ Wh2,
    unsigned short* __restrict__ whi, unsigned short* __restrict__ wlo,
    const int* __restrict__ src, const int* __restrict__ dst,
    int* __restrict__ cnt, int2* __restrict__ sd, int E)
{
    int t = blockIdx.x * 256 + threadIdx.x;
    if (t < 32768) {
        int e_ = t & 7, lane = (t >> 3) & 63, frag = (t >> 9) & 7, layer = t >> 12;
        int kt = frag >> 2, nt = frag & 3;
        int k = kt * 32 + ((lane >> 4) * 8) + e_;
        int n = nt * 16 + (lane & 15);
        const float* W;
        switch (layer) {
            case 0: W = We1; break;
            case 1: W = We2; break;
            case 2: W = Wp1; break;
            case 3: W = Wp2; break;
            case 4: W = Wh1; break;
            case 5: W = Wh2; break;
            case 6: W = Wp1 + 64 * 64; break;
            default: W = Wp1 + 128 * 64; break;
        }
        float w = W[k * 64 + n];
        short h = f2bf_hw(w);
        whi[t] = (unsigned short)h;
        wlo[t] = (unsigned short)f2bf_hw(w - bf2f_hw((unsigned short)h));
    }
    for (int i = t; i < E; i += gridDim.x * 256) {
        int d = dst[i];
        atomicAdd(&cnt[d], 1);
        sd[i] = make_int2(src[i], d);
    }
}

// ---- node pipeline via MFMA + CSR-fill tail. z_h/u stored bf16; u uses
// fragment-major [node][c15][nt]; z_hb stored via LDS row-read (8B/lane
// vectorized stores instead of 32 scalar 2B stores).
__global__ __launch_bounds__(256) void node_mfma(
    const float* __restrict__ h,
    const unsigned short* __restrict__ whi, const unsigned short* __restrict__ wlo,
    const float* __restrict__ Wa,
    unsigned short* __restrict__ z_hb,
    unsigned short* __restrict__ u_sb, unsigned short* __restrict__ u_db,
    float* __restrict__ as_, float* __restrict__ ad_,
    const int2* __restrict__ sd, int* __restrict__ cursor, int2* __restrict__ esrc,
    int N, int E)
{
    __shared__ float act[BM * 64];
    char* lds = (char*)act;
    const int lane  = threadIdx.x & 63;
    const int wave  = threadIdx.x >> 6;
    const int wrow0 = wave * 32;
    const long node0 = (long)blockIdx.x * BM;
    const int g   = lane >> 4;
    const int c15 = lane & 15;

    f32x4 acc[2][4];
    auto zacc = [&]() {
        #pragma unroll
        for (int mt = 0; mt < 2; ++mt)
            #pragma unroll
            for (int nt = 0; nt < 4; ++nt)
                #pragma unroll
                for (int rr = 0; rr < 4; ++rr) acc[mt][nt][rr] = 0.f;
    };

    auto mfma_layer = [&](int layer) {
        #pragma unroll
        for (int kt = 0; kt < 2; ++kt) {
            bf16x8 ah[2], al[2];
            #pragma unroll
            for (int mt = 0; mt < 2; ++mt) {
                f32x4 a0, a1;
                if (layer == 4) {           // A from global h
                    long nr = node0 + wrow0 + mt * 16 + c15; if (nr >= N) nr = N - 1;
                    const f32x4* p = (const f32x4*)(h + nr * 64 + kt * 32 + g * 8);
                    a0 = p[0];
                    a1 = p[1];
                } else {
                    int row = wrow0 + mt * 16 + c15;
                    int cb  = kt * 128 + g * 32;
                    a0 = *(const f32x4*)(lds + swz(row, cb));
                    a1 = *(const f32x4*)(lds + swz(row, cb + 16));
                }
                split8(a0, a1, ah[mt], al[mt]);
            }
            __builtin_amdgcn_s_setprio(1);
            #pragma unroll
            for (int nt = 0; nt < 4; ++nt) {
                int fo = ((layer * 8 + kt * 4 + nt) * 64 + lane) * 8;
                bf16x8 bh = *(const bf16x8*)(whi + fo);
                bf16x8 bl = *(const bf16x8*)(wlo + fo);
                #pragma unroll
                for (int mt = 0; mt < 2; ++mt) {
                    acc[mt][nt] = __builtin_amdgcn_mfma_f32_16x16x32_bf16(ah[mt], bh, acc[mt][nt], 0, 0, 0);
                    acc[mt][nt] = __builtin_amdgcn_mfma_f32_16x16x32_bf16(ah[mt], bl, acc[mt][nt], 0, 0, 0);
                    acc[mt][nt] = __builtin_amdgcn_mfma_f32_16x16x32_bf16(al[mt], bh, acc[mt][nt], 0, 0, 0);
                }
            }
            __builtin_amdgcn_s_setprio(0);
        }
    };

    auto writeback = [&](bool relu) {
        #pragma unroll
        for (int mt = 0; mt < 2; ++mt)
            #pragma unroll
            for (int nt = 0; nt < 4; ++nt)
                #pragma unroll
                for (int rr = 0; rr < 4; ++rr) {
                    int row  = wrow0 + mt * 16 + g * 4 + rr;
                    int colb = (nt * 16 + c15) * 4;
                    float v = acc[mt][nt][rr];
                    if (relu) v = fmaxf(v, 0.f);
                    *(float*)(lds + swz(row, colb)) = v;
                }
    };

    // fragment-major bf16 store: lane holds all 4 nt values for (node, c15)
    auto store_u = [&](unsigned short* __restrict__ out) {
        #pragma unroll
        for (int mt = 0; mt < 2; ++mt)
            #pragma unroll
            for (int rr = 0; rr < 4; ++rr) {
                long nr = node0 + wrow0 + mt * 16 + g * 4 + rr; if (nr >= N) nr = N - 1;
                ushort4 v;
                v.x = (unsigned short)f2bf_hw(acc[mt][0][rr]);
                v.y = (unsigned short)f2bf_hw(acc[mt][1][rr]);
                v.z = (unsigned short)f2bf_hw(acc[mt][2][rr]);
                v.w = (unsigned short)f2bf_hw(acc[mt][3][rr]);
                *(ushort4*)(out + nr * 64 + c15 * 4) = v;
            }
    };

    // L1: t1 = relu(h @ Wh1)
    zacc(); mfma_layer(4); writeback(true);
    // L2: z_h = t1 @ Wh2
    zacc(); mfma_layer(5);

    // as = z_h . Wa[64:128], ad = z_h . Wa[128:192]  (Wa loaded at use)
    {
        float was[4], wad[4];
        #pragma unroll
        for (int nt = 0; nt < 4; ++nt) {
            was[nt] = Wa[64  + nt * 16 + c15];
            wad[nt] = Wa[128 + nt * 16 + c15];
        }
        #pragma unroll
        for (int mt = 0; mt < 2; ++mt) {
            float ps[4], pd[4];
            #pragma unroll
            for (int rr = 0; rr < 4; ++rr) {
                ps[rr] = acc[mt][0][rr] * was[0] + acc[mt][1][rr] * was[1]
                       + acc[mt][2][rr] * was[2] + acc[mt][3][rr] * was[3];
                pd[rr] = acc[mt][0][rr] * wad[0] + acc[mt][1][rr] * wad[1]
                       + acc[mt][2][rr] * wad[2] + acc[mt][3][rr] * wad[3];
            }
            #pragma unroll
            for (int off = 1; off < 16; off <<= 1)
                #pragma unroll
                for (int rr = 0; rr < 4; ++rr) {
                    ps[rr] += __shfl_xor(ps[rr], off);
                    pd[rr] += __shfl_xor(pd[rr], off);
                }
            if (c15 == 0) {
                #pragma unroll
                for (int rr = 0; rr < 4; ++rr) {
                    long nr = node0 + wrow0 + mt * 16 + g * 4 + rr; if (nr >= N) nr = N - 1;
                    as_[nr] = ps[rr];
                    ad_[nr] = pd[rr];
                }
            }
        }
    }
    writeback(false);   // z_h -> LDS for L3/L4 and the vectorized z_hb store

    // z_hb via LDS row-read: 8 x (ds_read_b128 -> cvt -> 8B store), coalesced
    #pragma unroll
    for (int q = 0; q < 8; ++q) {
        int seg  = q * 64 + lane;
        int row  = seg >> 4;            // 0..31 within wave tile
        int colb = (seg & 15) * 16;     // byte col
        long nr = node0 + wrow0 + row;
        if (nr < N) {
            f32x4 v = *(const f32x4*)(lds + swz(wrow0 + row, colb));
            ushort4 o;
            o.x = (unsigned short)f2bf_hw(v[0]);
            o.y = (unsigned short)f2bf_hw(v[1]);
            o.z = (unsigned short)f2bf_hw(v[2]);
            o.w = (unsigned short)f2bf_hw(v[3]);
            *(ushort4*)(z_hb + nr * 64 + colb / 4) = o;
        }
    }

    // L3: u_s = z_h @ Wp1[64:128]
    zacc(); mfma_layer(6); store_u(u_sb);
    // L4: u_d = z_h @ Wp1[128:192]  (LDS still holds z_h)
    zacc(); mfma_layer(7); store_u(u_db);

    // CSR fill tail (folded; cursor ready — scans run before node)
    {
        int tid = blockIdx.x * 256 + threadIdx.x;
        int stride = gridDim.x * 256;
        for (int i = tid; i < E; i += stride) {
            int2 v = sd[i];
            int p = atomicAdd(&cursor[v.y], 1);
            esrc[p] = make_int2(i, v.x);
        }
    }
}

// ---- edge pipeline (R13 schedule — the local optimum). L4 output now goes
// through the LDS tile and is stored as 8 coalesced dwordx4/lane instead of
// 32 scattered dword stores.
__global__ __launch_bounds__(256) void edge_mfma(
    const float* __restrict__ e, const int2* __restrict__ sd,
    const unsigned short* __restrict__ u_sb, const unsigned short* __restrict__ u_db,
    const float* __restrict__ as_, const float* __restrict__ ad_,
    const unsigned short* __restrict__ whi, const unsigned short* __restrict__ wlo,
    const float* __restrict__ Wa, const float* __restrict__ bp1, const float* __restrict__ bp2,
    float* __restrict__ eproj, float* __restrict__ abuf, int E)
{
    __shared__ float act[BM * 64];
    char* lds = (char*)act;
    const int lane  = threadIdx.x & 63;
    const int wave  = threadIdx.x >> 6;
    const int wrow0 = wave * 32;
    const long edge0 = (long)blockIdx.x * BM;
    const int g   = lane >> 4;
    const int c15 = lane & 15;

    // (1) e-row loads FIRST — retire before the gathers (vmcnt is in-order)
    f32x4 ea[2][2][2];   // [mt][kt][half]
    #pragma unroll
    for (int mt = 0; mt < 2; ++mt) {
        long er = edge0 + wrow0 + mt * 16 + c15; if (er >= E) er = E - 1;
        #pragma unroll
        for (int kt = 0; kt < 2; ++kt) {
            const f32x4* p = (const f32x4*)(e + er * 64 + kt * 32 + g * 8);
            ea[mt][kt][0] = __builtin_nontemporal_load(p);
            ea[mt][kt][1] = __builtin_nontemporal_load(p + 1);
        }
    }

    // (2) per-edge gathers issued second — consumed at attention / L3
    float uv[2][4][4], asv[2][4];
    #pragma unroll
    for (int mt = 0; mt < 2; ++mt)
        #pragma unroll
        for (int rr = 0; rr < 4; ++rr) {
            long er = edge0 + wrow0 + mt * 16 + g * 4 + rr; if (er >= E) er = E - 1;
            int2 sdv = sd[er];
            int sn = sdv.x, dn = sdv.y;
            ushort4 a = *(const ushort4*)(u_sb + (size_t)sn * 64 + c15 * 4);
            ushort4 b = *(const ushort4*)(u_db + (size_t)dn * 64 + c15 * 4);
            uv[mt][0][rr] = bf2f_hw(a.x) + bf2f_hw(b.x);
            uv[mt][1][rr] = bf2f_hw(a.y) + bf2f_hw(b.y);
            uv[mt][2][rr] = bf2f_hw(a.z) + bf2f_hw(b.z);
            uv[mt][3][rr] = bf2f_hw(a.w) + bf2f_hw(b.w);
            asv[mt][rr] = as_[sn] + ad_[dn];
        }

    f32x4 acc[2][4];
    auto zacc = [&]() {
        #pragma unroll
        for (int mt = 0; mt < 2; ++mt)
            #pragma unroll
            for (int nt = 0; nt < 4; ++nt)
                #pragma unroll
                for (int rr = 0; rr < 4; ++rr) acc[mt][nt][rr] = 0.f;
    };

    auto mfma_layer = [&](int layer) {
        #pragma unroll
        for (int kt = 0; kt < 2; ++kt) {
            bf16x8 ah[2], al[2];
            #pragma unroll
            for (int mt = 0; mt < 2; ++mt) {
                f32x4 a0, a1;
                if (layer == 0) {   // pre-loaded registers
                    a0 = ea[mt][kt][0];
                    a1 = ea[mt][kt][1];
                } else {
                    int row = wrow0 + mt * 16 + c15;
                    int cb  = kt * 128 + g * 32;
                    a0 = *(const f32x4*)(lds + swz(row, cb));
                    a1 = *(const f32x4*)(lds + swz(row, cb + 16));
                }
                split8(a0, a1, ah[mt], al[mt]);
            }
            __builtin_amdgcn_s_setprio(1);
            #pragma unroll
            for (int nt = 0; nt < 4; ++nt) {
                int fo = ((layer * 8 + kt * 4 + nt) * 64 + lane) * 8;
                bf16x8 bh = *(const bf16x8*)(whi + fo);
                bf16x8 bl = *(const bf16x8*)(wlo + fo);
                #pragma unroll
                for (int mt = 0; mt < 2; ++mt) {
                    acc[mt][nt] = __builtin_amdgcn_mfma_f32_16x16x32_bf16(ah[mt], bh, acc[mt][nt], 0, 0, 0);
                    acc[mt][nt] = __builtin_amdgcn_mfma_f32_16x16x32_bf16(ah[mt], bl, acc[mt][nt], 0, 0, 0);
                    acc[mt][nt] = __builtin_amdgcn_mfma_f32_16x16x32_bf16(al[mt], bh, acc[mt][nt], 0, 0, 0);
                }
            }
            __builtin_amdgcn_s_setprio(0);
        }
    };

    auto writeback = [&](bool relu) {
        #pragma unroll
        for (int mt = 0; mt < 2; ++mt)
            #pragma unroll
            for (int nt = 0; nt < 4; ++nt)
                #pragma unroll
                for (int rr = 0; rr < 4; ++rr) {
                    int row  = wrow0 + mt * 16 + g * 4 + rr;
                    int colb = (nt * 16 + c15) * 4;
                    float v = acc[mt][nt][rr];
                    if (relu) v = fmaxf(v, 0.f);
                    *(float*)(lds + swz(row, colb)) = v;
                }
    };

    // L1: t1 = relu(e @ We1)
    zacc(); mfma_layer(0); writeback(true);
    // L2: z_e = t1 @ We2
    zacc(); mfma_layer(1);

    // attention: ae = z_e . Wa[0:64]; a = relu(ae + as[src] + ad[dst])
    {
        float waf[4];
        #pragma unroll
        for (int nt = 0; nt < 4; ++nt) waf[nt] = Wa[nt * 16 + c15];
        #pragma unroll
        for (int mt = 0; mt < 2; ++mt) {
            float part[4];
            #pragma unroll
            for (int rr = 0; rr < 4; ++rr)
                part[rr] = acc[mt][0][rr] * waf[0] + acc[mt][1][rr] * waf[1]
                         + acc[mt][2][rr] * waf[2] + acc[mt][3][rr] * waf[3];
            #pragma unroll
            for (int off = 1; off < 16; off <<= 1)
                #pragma unroll
                for (int rr = 0; rr < 4; ++rr) part[rr] += __shfl_xor(part[rr], off);
            if (c15 == 0) {
                #pragma unroll
                for (int rr = 0; rr < 4; ++rr) {
                    long er = edge0 + wrow0 + mt * 16 + g * 4 + rr; if (er >= E) er = E - 1;
                    __builtin_nontemporal_store(fmaxf(part[rr] + asv[mt][rr], 0.f), abuf + er);
                }
            }
        }
    }
    writeback(false);

    // L3: t2 = relu(z_e @ Wp1top + uv + bp1)
    zacc(); mfma_layer(2);
    {
        float b1f[4];
        #pragma unroll
        for (int nt = 0; nt < 4; ++nt) b1f[nt] = bp1[nt * 16 + c15];
        #pragma unroll
        for (int mt = 0; mt < 2; ++mt)
            #pragma unroll
            for (int nt = 0; nt < 4; ++nt)
                #pragma unroll
                for (int rr = 0; rr < 4; ++rr)
                    acc[mt][nt][rr] += uv[mt][nt][rr] + b1f[nt];
    }
    writeback(true);

    // L4: eproj = relu(t2 @ Wp2 + bp2) — bias+relu into LDS, then coalesced
    // dwordx4 nontemporal stores (8/lane, 1KB per instruction per wave)
    zacc(); mfma_layer(3);
    {
        float b2f[4];
        #pragma unroll
        for (int nt = 0; nt < 4; ++nt) b2f[nt] = bp2[nt * 16 + c15];
        #pragma unroll
        for (int mt = 0; mt < 2; ++mt)
            #pragma unroll
            for (int nt = 0; nt < 4; ++nt)
                #pragma unroll
                for (int rr = 0; rr < 4; ++rr)
                    acc[mt][nt][rr] += b2f[nt];
    }
    writeback(true);
    #pragma unroll
    for (int q = 0; q < 8; ++q) {
        int seg  = q * 64 + lane;
        int row  = seg >> 4;            // 0..31 within wave tile
        int colb = (seg & 15) * 16;     // byte col
        long er = edge0 + wrow0 + row;
        if (er < E) {
            f32x4 v = *(const f32x4*)(lds + swz(wrow0 + row, colb));
            __builtin_nontemporal_store(v, (f32x4*)(eproj + er * 64 + colb / 4));
        }
    }
}

// ---- CSR scan ----
__global__ __launch_bounds__(256) void k_scan1(
    const int* __restrict__ cnt, int* __restrict__ ofs, int* __restrict__ bsum, int N)
{
    __shared__ int sm[256];
    int t = threadIdx.x, i = blockIdx.x * 256 + t;
    int v = (i < N) ? cnt[i] : 0;
    sm[t] = v;
    __syncthreads();
    #pragma unroll
    for (int off = 1; off < 256; off <<= 1) {
        int tmp = (t >= off) ? sm[t - off] : 0;
        __syncthreads();
        sm[t] += tmp;
        __syncthreads();
    }
    if (i < N) ofs[i] = sm[t] - v;
    if (t == 255) bsum[blockIdx.x] = sm[255];
}

__global__ __launch_bounds__(256) void k_scan2(int* __restrict__ bsum, int NB)
{
    __shared__ int sm[256];
    int t = threadIdx.x;
    int v = (t < NB) ? bsum[t] : 0;
    sm[t] = v;
    __syncthreads();
    #pragma unroll
    for (int off = 1; off < 256; off <<= 1) {
        int tmp = (t >= off) ? sm[t - off] : 0;
        __syncthreads();
        sm[t] += tmp;
        __syncthreads();
    }
    if (t < NB) bsum[t] = sm[t] - v;   // exclusive
}

__global__ __launch_bounds__(256) void k_scan3(
    int* __restrict__ ofs, int* __restrict__ cursor,
    const int* __restrict__ bsum, int N)
{
    int i = blockIdx.x * 256 + threadIdx.x;
    if (i < N) {
        int o = ofs[i] + bsum[blockIdx.x];
        ofs[i] = o;
        cursor[i] = o;
    }
}

// ---- fused segment softmax + weighted gather: 1 wave/node.
// z_h gathered as bf16 (ushort4, 8B/lane) — half the random-read bytes.
__global__ __launch_bounds__(256) void k_aggregate(
    const float* __restrict__ abuf, const int2* __restrict__ esrc,
    const int* __restrict__ ofs, const int* __restrict__ cnt,
    const unsigned short* __restrict__ z_hb, float* __restrict__ hout, int N)
{
    int wid  = (blockIdx.x * 256 + threadIdx.x) >> 6;
    int lane = threadIdx.x & 63;
    if (wid >= N) return;
    int grp = lane >> 4, c15 = lane & 15;

    int begin = ofs[wid];
    int deg   = cnt[wid];

    float4 acc = make_float4(0.f, 0.f, 0.f, 0.f);
    float inv_s;

    if (deg <= 64) {
        float a = 0.f; int sidx = 0;
        if (lane < deg) {
            int2 es = esrc[begin + lane];
            a    = abuf[es.x];
            sidx = es.y;
        }
        float m = a;
        #pragma unroll
        for (int off = 32; off; off >>= 1) m = fmaxf(m, __shfl_xor(m, off));

        float ex = (lane < deg) ? __expf(a - m) : 0.f;
        float s = ex;
        #pragma unroll
        for (int off = 32; off; off >>= 1) s += __shfl_xor(s, off);
        inv_s = 1.0f / fmaxf(s, 1e-9f);

        int trips = (deg + 3) >> 2;
        for (int i = 0; i < trips; ++i) {
            int k = grp + 4 * i;
            float w  = __shfl(ex,   k & 63);
            int   sk = __shfl(sidx, k & 63);
            if (k < deg) {
                const ushort4 v = *(const ushort4*)(z_hb + (size_t)sk * DIM + c15 * 4);
                acc.x = fmaf(w, bf2f_hw(v.x), acc.x);
                acc.y = fmaf(w, bf2f_hw(v.y), acc.y);
                acc.z = fmaf(w, bf2f_hw(v.z), acc.z);
                acc.w = fmaf(w, bf2f_hw(v.w), acc.w);
            }
        }
    } else {
        float m = 0.f;
        for (int k = lane; k < deg; k += 64) m = fmaxf(m, abuf[esrc[begin + k].x]);
        #pragma unroll
        for (int off = 32; off; off >>= 1) m = fmaxf(m, __shfl_xor(m, off));

        float s = 0.f;
        for (int k = lane; k < deg; k += 64) s += __expf(abuf[esrc[begin + k].x] - m);
        #pragma unroll
        for (int off = 32; off; off >>= 1) s += __shfl_xor(s, off);
        inv_s = 1.0f / fmaxf(s, 1e-9f);

        for (int k = grp; k < deg; k += 4) {
            int2 es = esrc[begin + k];
            float w = __expf(abuf[es.x] - m);
            const ushort4 v = *(const ushort4*)(z_hb + (size_t)es.y * DIM + c15 * 4);
            acc.x = fmaf(w, bf2f_hw(v.x), acc.x);
            acc.y = fmaf(w, bf2f_hw(v.y), acc.y);
            acc.z = fmaf(w, bf2f_hw(v.z), acc.z);
            acc.w = fmaf(w, bf2f_hw(v.w), acc.w);
        }
    }

    #pragma unroll
    for (int off = 16; off <= 32; off <<= 1) {
        acc.x += __shfl_xor(acc.x, off);
        acc.y += __shfl_xor(acc.y, off);
        acc.z += __shfl_xor(acc.z, off);
        acc.w += __shfl_xor(acc.w, off);
    }
    if (grp == 0) {
        float4 r = make_float4(fmaxf(acc.x * inv_s, 0.f), fmaxf(acc.y * inv_s, 0.f),
                               fmaxf(acc.z * inv_s, 0.f), fmaxf(acc.w * inv_s, 0.f));
        *(float4*)(hout + (size_t)wid * DIM + c15 * 4) = r;
    }
}

extern "C" void kernel_launch(void* const* d_in, const int* in_sizes, int n_in,
                              void* d_out, int out_size, void* d_ws, size_t ws_size,
                              hipStream_t stream)
{
    const float* h   = (const float*)d_in[0];
    const float* e   = (const float*)d_in[1];
    const int*   src = (const int*)d_in[2];
    const int*   dst = (const int*)d_in[3];
    const float* Wh1 = (const float*)d_in[4];
    const float* Wh2 = (const float*)d_in[5];
    const float* We1 = (const float*)d_in[6];
    const float* We2 = (const float*)d_in[7];
    const float* Wp1 = (const float*)d_in[8];
    const float* bp1 = (const float*)d_in[9];
    const float* Wp2 = (const float*)d_in[10];
    const float* bp2 = (const float*)d_in[11];
    const float* Wa  = (const float*)d_in[12];

    const int N = in_sizes[0] / DIM;
    const int E = in_sizes[1] / DIM;

    float* ws   = (float*)d_ws;
    unsigned short* z_hb = (unsigned short*)ws;  ws += (size_t)N * DIM / 2;
    unsigned short* u_sb = (unsigned short*)ws;  ws += (size_t)N * DIM / 2;
    unsigned short* u_db = (unsigned short*)ws;  ws += (size_t)N * DIM / 2;
    float* as_  = ws;  ws += N;
    float* ad_  = ws;  ws += N;
    float* abuf = ws;  ws += E;
    int* cnt    = (int*)ws;  ws += N;
    int* ofs    = (int*)ws;  ws += N;
    int* cursor = (int*)ws;  ws += N;
    int2* esrc  = (int2*)ws; ws += (size_t)2 * E;
    int2* sd    = (int2*)ws; ws += (size_t)2 * E;
    int* bsum   = (int*)ws;  ws += 256;
    unsigned short* whi = (unsigned short*)ws;  ws += 32768 / 2;
    unsigned short* wlo = (unsigned short*)ws;  ws += 32768 / 2;

    float* hout  = (float*)d_out;
    float* eproj = hout + (size_t)N * DIM;

    const int NB = (N + 255) / 256;   // N=50000 -> 196 <= 256

    hipMemsetAsync(cnt, 0, (size_t)N * sizeof(int), stream);

    k_prep_hist<<<(E + 255) / 256, 256, 0, stream>>>(
        We1, We2, Wp1, Wp2, Wh1, Wh2, whi, wlo, src, dst, cnt, sd, E);

    k_scan1<<<NB, 256, 0, stream>>>(cnt, ofs, bsum, N);
    k_scan2<<<1, 256, 0, stream>>>(bsum, NB);
    k_scan3<<<NB, 256, 0, stream>>>(ofs, cursor, bsum, N);

    node_mfma<<<(N + BM - 1) / BM, 256, 0, stream>>>(
        h, whi, wlo, Wa, z_hb, u_sb, u_db, as_, ad_, sd, cursor, esrc, N, E);

    edge_mfma<<<(E + BM - 1) / BM, 256, 0, stream>>>(
        e, sd, u_sb, u_db, as_, ad_, whi, wlo, Wa, bp1, bp2,
        eproj, abuf, E);

    k_aggregate<<<((N * 64) + 255) / 256, 256, 0, stream>>>(
        abuf, esrc, ofs, cnt, z_hb, hout, N);
}